// Round 4
// baseline (921.766 us; speedup 1.0000x reference)
//
#include <hip/hip_runtime.h>
#include <hip/hip_bf16.h>

#define NN 50000
#define EE 1600000
#define GG 500

typedef __bf16 bf16x8 __attribute__((ext_vector_type(8)));
typedef float  f32x4  __attribute__((ext_vector_type(4)));

__device__ __forceinline__ float b2f(ushort u) {
  return __uint_as_float(((unsigned)u) << 16);
}
__device__ __forceinline__ ushort f2b(float f) {
  unsigned u = __float_as_uint(f);
  unsigned r = (u + 0x7fff + ((u >> 16) & 1)) >> 16;   // RNE
  return (ushort)r;
}

// ---------------- graph preprocessing ----------------

__global__ void deg_hist_kernel(const int* __restrict__ src, const int* __restrict__ dst,
                                const float* __restrict__ ea, float* __restrict__ deg,
                                int* __restrict__ cnt, int* __restrict__ rank, int e) {
  int i = blockIdx.x * blockDim.x + threadIdx.x;
  if (i < e) {
    atomicAdd(&deg[src[i]], ea[i]);
    rank[i] = atomicAdd(&cnt[dst[i]], 1);
  }
}

__global__ void dinv_kernel(float* __restrict__ deg, int n) {
  int i = blockIdx.x * blockDim.x + threadIdx.x;
  if (i < n) { float d = deg[i]; deg[i] = (d > 0.f) ? (1.0f / sqrtf(d)) : 0.f; }
}

__global__ void scan1(const int* __restrict__ cnt, int* __restrict__ partial,
                      int* __restrict__ bsum, int n) {
  __shared__ int s[256];
  int t = threadIdx.x, i = blockIdx.x * 256 + t;
  int v = (i < n) ? cnt[i] : 0;
  s[t] = v; __syncthreads();
  for (int off = 1; off < 256; off <<= 1) {
    int xv = (t >= off) ? s[t - off] : 0;
    __syncthreads(); s[t] += xv; __syncthreads();
  }
  if (i < n) partial[i] = s[t];
  if (t == 255) bsum[blockIdx.x] = s[255];
}

__global__ void scan2(int* __restrict__ bsum, int nb) {
  __shared__ int s[256];
  int t = threadIdx.x;
  int v = (t < nb) ? bsum[t] : 0;
  s[t] = v; __syncthreads();
  for (int off = 1; off < 256; off <<= 1) {
    int xv = (t >= off) ? s[t - off] : 0;
    __syncthreads(); s[t] += xv; __syncthreads();
  }
  if (t < nb) bsum[t] = s[t];
}

__global__ void scan3(const int* __restrict__ partial, const int* __restrict__ bsum,
                      int* __restrict__ rowptr, int n) {
  int i = blockIdx.x * 256 + threadIdx.x;
  if (i < n) {
    int off = (blockIdx.x > 0) ? bsum[blockIdx.x - 1] : 0;
    rowptr[i + 1] = partial[i] + off;
    if (i == 0) rowptr[0] = 0;
  }
}

// atomic-free: pos = rowptr[d] + rank (rank captured during histogram)
__global__ void scatter_kernel(const int* __restrict__ src, const int* __restrict__ dst,
                               const float* __restrict__ ea, const float* __restrict__ dinv,
                               const int* __restrict__ rowptr, const int* __restrict__ rank,
                               uint2* __restrict__ edges, int e) {
  int i = blockIdx.x * blockDim.x + threadIdx.x;
  if (i < e) {
    int s = src[i], d = dst[i];
    float w = -dinv[s] * ea[i] * dinv[d];
    edges[rowptr[d] + rank[i]] = make_uint2((unsigned)s, __float_as_uint(w));
  }
}

// ---------------- dtype conversions ----------------

__global__ void cvt_x(const float* __restrict__ x, ushort* __restrict__ xb, int n4) {
  int i = blockIdx.x * 256 + threadIdx.x;
  if (i < n4) {
    float4 v = ((const float4*)x)[i];
    ushort4 o;
    o.x = f2b(v.x); o.y = f2b(v.y); o.z = f2b(v.z); o.w = f2b(v.w);
    ((ushort4*)xb)[i] = o;
  }
}

// Wt1[320][128] = W1[j>>6][k][j&63]; Wt2[320][64]; Wt3[128][320] = W3stack^T
__global__ void cvt_w(const float* __restrict__ W1, const float* __restrict__ W2,
                      const float* __restrict__ W3, ushort* __restrict__ Wt1,
                      ushort* __restrict__ Wt2, ushort* __restrict__ Wt3) {
  int i = blockIdx.x * 256 + threadIdx.x;
  if (i < 320 * 128) {
    int j = i / 128, k = i % 128;
    Wt1[i] = f2b(W1[((size_t)(j >> 6) * 128 + k) * 64 + (j & 63)]);
  } else if (i < 320 * 128 + 320 * 64) {
    int t = i - 320 * 128; int j = t / 64, k = t % 64;
    Wt2[t] = f2b(W2[((size_t)(j >> 6) * 64 + k) * 64 + (j & 63)]);
  } else if (i < 320 * 128 + 320 * 64 + 128 * 320) {
    int t = i - 320 * 128 - 320 * 64; int j = t / 320, k = t % 320;
    Wt3[t] = f2b(W3[(size_t)k * 128 + j]);
  }
}

// ---------------- sparse propagation V2: half-wave, 2 bf16 features/lane -----
// out = alpha * prop(g) + c1*a1 + c2*a2   [+ bias, relu]
// Wave = 1 dst node; lanes 0-31 (half 0) process even edges, 32-63 odd edges.
// Lane holds features {2fl, 2fl+1}; halves combined once via shfl_xor(32).

template<int NADD, bool RELUB>
__global__ __launch_bounds__(256) void prop_kernel(
    const int* __restrict__ rowptr, const uint2* __restrict__ edges,
    const ushort* __restrict__ g, int sg,
    const ushort* __restrict__ a1, int sa1, float c1,
    const ushort* __restrict__ a2, int sa2, float c2,
    const float* __restrict__ bias,
    ushort* __restrict__ out, int so, int n, float alpha)
{
  int wv = blockIdx.x * 4 + (threadIdx.x >> 6);
  wv = __builtin_amdgcn_readfirstlane(wv);
  const int lane = threadIdx.x & 63;
  const int half = lane >> 5;
  const int fl   = lane & 31;
  if (wv >= n) return;
  const int e0 = __builtin_amdgcn_readfirstlane(rowptr[wv]);
  const int e1 = __builtin_amdgcn_readfirstlane(rowptr[wv + 1]);

  float a00 = 0.f, a01 = 0.f, a10 = 0.f, a11 = 0.f;
  int j = e0;
  for (; j + 4 <= e1; j += 4) {
    uint2 p0 = edges[j + half];
    uint2 p1 = edges[j + 2 + half];
    uint v0 = *(const uint*)&g[(size_t)p0.x * sg + fl * 2];
    uint v1 = *(const uint*)&g[(size_t)p1.x * sg + fl * 2];
    float w0 = __uint_as_float(p0.y);
    float w1 = __uint_as_float(p1.y);
    a00 += w0 * __uint_as_float(v0 << 16);
    a01 += w0 * __uint_as_float(v0 & 0xffff0000u);
    a10 += w1 * __uint_as_float(v1 << 16);
    a11 += w1 * __uint_as_float(v1 & 0xffff0000u);
  }
  for (; j < e1; j += 2) {
    int jj = j + half;
    if (jj < e1) {
      uint2 p = edges[jj];
      uint v = *(const uint*)&g[(size_t)p.x * sg + fl * 2];
      float w = __uint_as_float(p.y);
      a00 += w * __uint_as_float(v << 16);
      a01 += w * __uint_as_float(v & 0xffff0000u);
    }
  }
  float r0 = a00 + a10;
  float r1 = a01 + a11;
  r0 += __shfl_xor(r0, 32, 64);
  r1 += __shfl_xor(r1, 32, 64);
  r0 *= alpha; r1 *= alpha;
  if constexpr (NADD >= 1) {
    uint u = *(const uint*)&a1[(size_t)wv * sa1 + fl * 2];
    r0 += c1 * __uint_as_float(u << 16);
    r1 += c1 * __uint_as_float(u & 0xffff0000u);
  }
  if constexpr (NADD >= 2) {
    uint u = *(const uint*)&a2[(size_t)wv * sa2 + fl * 2];
    r0 += c2 * __uint_as_float(u << 16);
    r1 += c2 * __uint_as_float(u & 0xffff0000u);
  }
  if constexpr (RELUB) {
    float2 bv = ((const float2*)bias)[fl];
    r0 = fmaxf(r0 + bv.x, 0.f);
    r1 = fmaxf(r1 + bv.y, 0.f);
  }
  if (half == 0) {
    uint o = (uint)f2b(r0) | ((uint)f2b(r1) << 16);
    *(uint*)&out[(size_t)wv * so + fl * 2] = o;
  }
}

// ---------------- MFMA GEMM: C[n x Co](bf16) = A[n x Ci](bf16) @ Wt^T --------
// Wt is [Co][Ci] bf16 (B^T row-major). No LDS: B-frags from L1/L2,
// A-frags from global. Block = 4 waves; wave = 4 strips of 16 rows x 64 cols.

template<int Ci, int Co, bool BR>
__global__ __launch_bounds__(256) void gemm_mfma(const ushort* __restrict__ A,
    const ushort* __restrict__ Wt, const float* __restrict__ bias,
    ushort* __restrict__ C, int n)
{
  const int lane = threadIdx.x & 63;
  const int wid  = threadIdx.x >> 6;
  const int rb = blockIdx.x * 256;
  const int cb = blockIdx.y * 64;
  const int lr = lane & 15;            // row/col within fragment
  const int lk = (lane >> 4) << 3;     // k offset: 0,8,16,24
  f32x4 acc[4][4] = {};

  for (int kc = 0; kc < Ci; kc += 64) {
    bf16x8 bfrag[2][4];
    #pragma unroll
    for (int ks = 0; ks < 2; ++ks)
      #pragma unroll
      for (int nt = 0; nt < 4; ++nt)
        bfrag[ks][nt] = *(const bf16x8*)&Wt[(size_t)(cb + nt * 16 + lr) * Ci + kc + ks * 32 + lk];
    #pragma unroll
    for (int s = 0; s < 4; ++s) {
      const int row = rb + (wid * 4 + s) * 16 + lr;
      const ushort* ap = &A[(size_t)row * Ci + kc + lk];
      #pragma unroll
      for (int ks = 0; ks < 2; ++ks) {
        bf16x8 af = {};
        if (row < n) af = *(const bf16x8*)(ap + ks * 32);
        #pragma unroll
        for (int nt = 0; nt < 4; ++nt)
          acc[s][nt] = __builtin_amdgcn_mfma_f32_16x16x32_bf16(af, bfrag[ks][nt], acc[s][nt], 0, 0, 0);
      }
    }
  }

  #pragma unroll
  for (int s = 0; s < 4; ++s) {
    #pragma unroll
    for (int nt = 0; nt < 4; ++nt) {
      const int col = cb + nt * 16 + lr;
      #pragma unroll
      for (int r = 0; r < 4; ++r) {
        const int row = rb + (wid * 4 + s) * 16 + ((lane >> 4) << 2) + r;
        if (row < n) {
          float v = acc[s][nt][r];
          if constexpr (BR) v = fmaxf(v + bias[col], 0.f);
          C[(size_t)row * Co + col] = f2b(v);
        }
      }
    }
  }
}

// ---------------- pooling + head ----------------

__global__ __launch_bounds__(128) void pool_kernel(const ushort* __restrict__ h,
    const int* __restrict__ batch, float* __restrict__ pooled,
    float* __restrict__ gcnt, int n) {
  const int f = threadIdx.x;           // 0..127
  const int i0 = blockIdx.x * 64;
  const int iend = min(i0 + 64, n);
  int cur = batch[i0];
  float acc = 0.f;
  int run = 0;
  for (int i = i0; i < iend; ++i) {
    int b = batch[i];
    float v = b2f(h[(size_t)i * 128 + f]);
    if (b != cur) {
      atomicAdd(&pooled[cur * 128 + f], acc);
      if (f == 0) atomicAdd(&gcnt[cur], (float)run);
      acc = 0.f; run = 0; cur = b;
    }
    acc += v; run++;
  }
  atomicAdd(&pooled[cur * 128 + f], acc);
  if (f == 0) atomicAdd(&gcnt[cur], (float)run);
}

__global__ __launch_bounds__(128) void head_kernel(const float* __restrict__ pooled,
    const float* __restrict__ gcnt, const float* __restrict__ Wl,
    const float* __restrict__ bl, float* __restrict__ outp)
{
  int g = blockIdx.x, t = threadIdx.x;
  float denom = fmaxf(gcnt[g], 1.f);
  float p = pooled[g * 128 + t] / denom;
  __shared__ float s0[128], s1[128];
  s0[t] = p * Wl[t * 2 + 0];
  s1[t] = p * Wl[t * 2 + 1];
  __syncthreads();
  for (int off = 64; off > 0; off >>= 1) {
    if (t < off) { s0[t] += s0[t + off]; s1[t] += s1[t + off]; }
    __syncthreads();
  }
  if (t == 0) {
    float a = s0[0] + bl[0], b = s1[0] + bl[1];
    float m = fmaxf(a, b);
    float z = logf(expf(a - m) + expf(b - m)) + m;
    outp[g * 2 + 0] = a - z;
    outp[g * 2 + 1] = b - z;
  }
}

// ---------------- launch ----------------

extern "C" void kernel_launch(void* const* d_in, const int* in_sizes, int n_in,
                              void* d_out, int out_size, void* d_ws, size_t ws_size,
                              hipStream_t stream) {
  const float* x   = (const float*)d_in[0];
  const int*   ei  = (const int*)d_in[1];
  const float* ea  = (const float*)d_in[2];
  const int* batch = (const int*)d_in[3];
  const float* W1  = (const float*)d_in[4];
  const float* lb1 = (const float*)d_in[5];
  const float* W2  = (const float*)d_in[6];
  const float* lb2 = (const float*)d_in[7];
  const float* W3  = (const float*)d_in[8];
  const float* lb3 = (const float*)d_in[9];
  const float* Wl  = (const float*)d_in[10];
  const float* bl  = (const float*)d_in[11];
  const int* srcv = ei;
  const int* dstv = ei + EE;

  char* w = (char*)d_ws;
  auto alloc = [&](size_t bytes) -> char* {
    char* p = w; w += (bytes + 255) & ~(size_t)255; return p;
  };
  float* deg    = (float*)alloc((size_t)NN * 4);          // becomes dinv
  int*   rowptr = (int*)alloc((size_t)(NN + 1) * 4);
  int*   cnt    = (int*)alloc((size_t)NN * 4);
  int*   bsum   = (int*)alloc(256 * 4);
  int*   rank   = (int*)alloc((size_t)EE * 4);
  uint2* edges  = (uint2*)alloc((size_t)EE * 8);
  ushort* xb    = (ushort*)alloc((size_t)NN * 128 * 2);
  ushort* Acat  = (ushort*)alloc((size_t)NN * 320 * 2);   // a_k / Clenshaw / Tx_k
  ushort* Bcat  = (ushort*)alloc((size_t)NN * 320 * 2);   // layer2 blocks; later h3
  ushort* h1    = (ushort*)alloc((size_t)NN * 64 * 2);
  ushort* Wt1   = (ushort*)alloc((size_t)320 * 128 * 2);
  ushort* Wt2   = (ushort*)alloc((size_t)320 * 64 * 2);
  ushort* Wt3   = (ushort*)alloc((size_t)128 * 320 * 2);
  float* pooled = (float*)alloc((size_t)(GG * 128 + GG) * 4);
  float* gcnt   = pooled + GG * 128;
  int*   partial = (int*)Acat;     // scan scratch (Acat unused until GEMM1)
  ushort* h3 = Bcat;               // layer-3 output reuses Bcat

  hipMemsetAsync(deg, 0, (size_t)NN * 4, stream);
  hipMemsetAsync(cnt, 0, (size_t)NN * 4, stream);
  hipMemsetAsync(pooled, 0, (size_t)(GG * 128 + GG) * 4, stream);

  deg_hist_kernel<<<(EE + 255) / 256, 256, 0, stream>>>(srcv, dstv, ea, deg, cnt, rank, EE);
  dinv_kernel<<<(NN + 255) / 256, 256, 0, stream>>>(deg, NN);
  const int nb = (NN + 255) / 256;  // 196
  scan1<<<nb, 256, 0, stream>>>(cnt, partial, bsum, NN);
  scan2<<<1, 256, 0, stream>>>(bsum, nb);
  scan3<<<nb, 256, 0, stream>>>(partial, bsum, rowptr, NN);
  scatter_kernel<<<(EE + 255) / 256, 256, 0, stream>>>(srcv, dstv, ea, deg, rowptr, rank,
                                                       edges, EE);

  cvt_x<<<(NN * 128 / 4 + 255) / 256, 256, 0, stream>>>(x, xb, NN * 128 / 4);
  cvt_w<<<(320 * 128 + 320 * 64 + 128 * 320 + 255) / 256, 256, 0, stream>>>(
      W1, W2, W3, Wt1, Wt2, Wt3);

  const int PG = (NN + 3) / 4;       // prop blocks (4 waves each)
  const int GX = (NN + 255) / 256;   // gemm row-blocks

  ushort* A0 = Acat + 0 * 64;  ushort* A1 = Acat + 1 * 64;  ushort* A2 = Acat + 2 * 64;
  ushort* A3 = Acat + 3 * 64;  ushort* A4 = Acat + 4 * 64;
  ushort* B0 = Bcat + 0 * 64;  ushort* B1 = Bcat + 1 * 64;  ushort* B2 = Bcat + 2 * 64;
  ushort* B3 = Bcat + 3 * 64;  ushort* B4 = Bcat + 4 * 64;
  const int S = 320;

  // ---- Layer 1 (Clenshaw): a_k = x @ W1_k  -> Acat[50000][320] ----
  gemm_mfma<128, 320, false><<<dim3(GX, 5), 256, 0, stream>>>(xb, Wt1, nullptr, Acat, NN);
  prop_kernel<1, false><<<PG, 256, 0, stream>>>(rowptr, edges, A4, S, A3, S, 1.f,
      nullptr, 0, 0.f, nullptr, A3, S, NN, 2.f);
  prop_kernel<2, false><<<PG, 256, 0, stream>>>(rowptr, edges, A3, S, A2, S, 1.f,
      A4, S, -1.f, nullptr, A2, S, NN, 2.f);
  prop_kernel<2, false><<<PG, 256, 0, stream>>>(rowptr, edges, A2, S, A1, S, 1.f,
      A3, S, -1.f, nullptr, A1, S, NN, 2.f);
  prop_kernel<2, true><<<PG, 256, 0, stream>>>(rowptr, edges, A1, S, A0, S, 1.f,
      A2, S, -1.f, lb1, h1, 64, NN, 1.f);

  // ---- Layer 2 (Clenshaw): a_k = h1 @ W2_k -> Bcat ----
  gemm_mfma<64, 320, false><<<dim3(GX, 5), 256, 0, stream>>>(h1, Wt2, nullptr, Bcat, NN);
  prop_kernel<1, false><<<PG, 256, 0, stream>>>(rowptr, edges, B4, S, B3, S, 1.f,
      nullptr, 0, 0.f, nullptr, B3, S, NN, 2.f);
  prop_kernel<2, false><<<PG, 256, 0, stream>>>(rowptr, edges, B3, S, B2, S, 1.f,
      B4, S, -1.f, nullptr, B2, S, NN, 2.f);
  prop_kernel<2, false><<<PG, 256, 0, stream>>>(rowptr, edges, B2, S, B1, S, 1.f,
      B3, S, -1.f, nullptr, B1, S, NN, 2.f);
  // h2 -> Acat block 0 (Tx0), strided
  prop_kernel<2, true><<<PG, 256, 0, stream>>>(rowptr, edges, B1, S, B0, S, 1.f,
      B2, S, -1.f, lb2, A0, S, NN, 1.f);

  // ---- Layer 3 (forward recursion, Tx_k in Acat blocks) ----
  prop_kernel<0, false><<<PG, 256, 0, stream>>>(rowptr, edges, A0, S, nullptr, 0, 0.f,
      nullptr, 0, 0.f, nullptr, A1, S, NN, 1.f);
  prop_kernel<1, false><<<PG, 256, 0, stream>>>(rowptr, edges, A1, S, A0, S, -1.f,
      nullptr, 0, 0.f, nullptr, A2, S, NN, 2.f);
  prop_kernel<1, false><<<PG, 256, 0, stream>>>(rowptr, edges, A2, S, A1, S, -1.f,
      nullptr, 0, 0.f, nullptr, A3, S, NN, 2.f);
  prop_kernel<1, false><<<PG, 256, 0, stream>>>(rowptr, edges, A3, S, A2, S, -1.f,
      nullptr, 0, 0.f, nullptr, A4, S, NN, 2.f);
  // h3 = relu([Tx0|..|Tx4] @ W3stack + b3)
  gemm_mfma<320, 128, true><<<dim3(GX, 2), 256, 0, stream>>>(Acat, Wt3, lb3, h3, NN);

  // ---- pool + head ----
  pool_kernel<<<(NN + 63) / 64, 128, 0, stream>>>(h3, batch, pooled, gcnt, NN);
  head_kernel<<<GG, 128, 0, stream>>>(pooled, gcnt, Wl, bl, (float*)d_out);
}

// Round 5
// 741.686 us; speedup vs baseline: 1.2428x; 1.2428x over previous
//
#include <hip/hip_runtime.h>
#include <hip/hip_bf16.h>

#define NN 50000
#define EE 1600000
#define GG 500

typedef __bf16 bf16x8 __attribute__((ext_vector_type(8)));
typedef float  f32x4  __attribute__((ext_vector_type(4)));

__device__ __forceinline__ float b2f(ushort u) {
  return __uint_as_float(((unsigned)u) << 16);
}
__device__ __forceinline__ ushort f2b(float f) {
  unsigned u = __float_as_uint(f);
  unsigned r = (u + 0x7fff + ((u >> 16) & 1)) >> 16;   // RNE
  return (ushort)r;
}
__device__ __forceinline__ float lo16(uint v) { return __uint_as_float(v << 16); }
__device__ __forceinline__ float hi16(uint v) { return __uint_as_float(v & 0xffff0000u); }
__device__ __forceinline__ int rfl(uint v) { return __builtin_amdgcn_readfirstlane((int)v); }
__device__ __forceinline__ float rflf(uint v) {
  return __uint_as_float((unsigned)__builtin_amdgcn_readfirstlane((int)v));
}

// ---------------- graph preprocessing ----------------

__global__ void deg_hist_kernel(const int* __restrict__ src, const int* __restrict__ dst,
                                const float* __restrict__ ea, float* __restrict__ deg,
                                int* __restrict__ cnt, int e) {
  int i = blockIdx.x * blockDim.x + threadIdx.x;
  if (i < e) {
    atomicAdd(&deg[src[i]], ea[i]);
    atomicAdd(&cnt[dst[i]], 1);
  }
}

__global__ void dinv_kernel(float* __restrict__ deg, int n) {
  int i = blockIdx.x * blockDim.x + threadIdx.x;
  if (i < n) { float d = deg[i]; deg[i] = (d > 0.f) ? (1.0f / sqrtf(d)) : 0.f; }
}

// scan over EVEN-PADDED counts: row i gets ceil(cnt/2)*2 slots (16B-aligned rows)
__global__ void scan1(const int* __restrict__ cnt, int* __restrict__ partial,
                      int* __restrict__ bsum, int n) {
  __shared__ int s[256];
  int t = threadIdx.x, i = blockIdx.x * 256 + t;
  int v = (i < n) ? ((cnt[i] + 1) & ~1) : 0;
  s[t] = v; __syncthreads();
  for (int off = 1; off < 256; off <<= 1) {
    int xv = (t >= off) ? s[t - off] : 0;
    __syncthreads(); s[t] += xv; __syncthreads();
  }
  if (i < n) partial[i] = s[t];
  if (t == 255) bsum[blockIdx.x] = s[255];
}

__global__ void scan2(int* __restrict__ bsum, int nb) {
  __shared__ int s[256];
  int t = threadIdx.x;
  int v = (t < nb) ? bsum[t] : 0;
  s[t] = v; __syncthreads();
  for (int off = 1; off < 256; off <<= 1) {
    int xv = (t >= off) ? s[t - off] : 0;
    __syncthreads(); s[t] += xv; __syncthreads();
  }
  if (t < nb) bsum[t] = s[t];
}

__global__ void scan3(const int* __restrict__ partial, const int* __restrict__ bsum,
                      int* __restrict__ rowptr, int n) {
  int i = blockIdx.x * 256 + threadIdx.x;
  if (i < n) {
    int off = (blockIdx.x > 0) ? bsum[blockIdx.x - 1] : 0;
    rowptr[i + 1] = partial[i] + off;
    if (i == 0) rowptr[0] = 0;
  }
}

__global__ void cursor_init(const int* __restrict__ rowptr, int* __restrict__ cursor, int n) {
  int i = blockIdx.x * 256 + threadIdx.x;
  if (i < n) cursor[i] = rowptr[i];
}

__global__ void scatter_kernel(const int* __restrict__ src, const int* __restrict__ dst,
                               const float* __restrict__ ea, const float* __restrict__ dinv,
                               int* __restrict__ cursor, uint2* __restrict__ edges, int e) {
  int i = blockIdx.x * blockDim.x + threadIdx.x;
  if (i < e) {
    int s = src[i], d = dst[i];
    float w = -dinv[s] * ea[i] * dinv[d];
    int pos = atomicAdd(&cursor[d], 1);
    edges[pos] = make_uint2((unsigned)s, __float_as_uint(w));
  }
}

// ---------------- dtype conversions ----------------

__global__ void cvt_x(const float* __restrict__ x, ushort* __restrict__ xb, int n4) {
  int i = blockIdx.x * 256 + threadIdx.x;
  if (i < n4) {
    float4 v = ((const float4*)x)[i];
    ushort4 o;
    o.x = f2b(v.x); o.y = f2b(v.y); o.z = f2b(v.z); o.w = f2b(v.w);
    ((ushort4*)xb)[i] = o;
  }
}

// Wt1[320][128] = W1[j>>6][k][j&63]; Wt2[320][64]; Wt3[128][320] = W3stack^T
__global__ void cvt_w(const float* __restrict__ W1, const float* __restrict__ W2,
                      const float* __restrict__ W3, ushort* __restrict__ Wt1,
                      ushort* __restrict__ Wt2, ushort* __restrict__ Wt3) {
  int i = blockIdx.x * 256 + threadIdx.x;
  if (i < 320 * 128) {
    int j = i / 128, k = i % 128;
    Wt1[i] = f2b(W1[((size_t)(j >> 6) * 128 + k) * 64 + (j & 63)]);
  } else if (i < 320 * 128 + 320 * 64) {
    int t = i - 320 * 128; int j = t / 64, k = t % 64;
    Wt2[t] = f2b(W2[((size_t)(j >> 6) * 64 + k) * 64 + (j & 63)]);
  } else if (i < 320 * 128 + 320 * 64 + 128 * 320) {
    int t = i - 320 * 128 - 320 * 64; int j = t / 320, k = t % 320;
    Wt3[t] = f2b(W3[(size_t)k * 128 + j]);
  }
}

// ---------------- sparse propagation V3 ----------------
// Wave = 1 dst node. Edges scalar-broadcast (SGPR); lanes 0-31 gather even
// edges' rows, lanes 32-63 odd edges' rows, 4B (2 bf16 feats) per lane.
// Rows even-padded with {src=0,w=0} so uint4 edge loads are 16B-aligned and
// no validity branches are needed. Halves combined once via shfl_xor(32).
// out = alpha * prop(g) + c1*a1 + c2*a2   [+ bias, relu]

template<int NADD, bool RELUB>
__global__ __launch_bounds__(256) void prop_kernel(
    const int* __restrict__ rowptr, const uint2* __restrict__ edges,
    const ushort* __restrict__ g, int sg,
    const ushort* __restrict__ a1, int sa1, float c1,
    const ushort* __restrict__ a2, int sa2, float c2,
    const float* __restrict__ bias,
    ushort* __restrict__ out, int so, int n, float alpha)
{
  int wv = blockIdx.x * 4 + (threadIdx.x >> 6);
  wv = __builtin_amdgcn_readfirstlane(wv);
  const int lane = threadIdx.x & 63;
  const int half = lane >> 5;
  const int fl   = lane & 31;
  if (wv >= n) return;
  const int e0 = __builtin_amdgcn_readfirstlane(rowptr[wv]);
  const int e1 = __builtin_amdgcn_readfirstlane(rowptr[wv + 1]);

  float r0 = 0.f, r1 = 0.f, s0 = 0.f, s1 = 0.f;
  int j = e0;
  for (; j + 8 <= e1; j += 8) {
    const uint4* ep = (const uint4*)(edges + j);   // 16B-aligned (rows even-padded)
    uint4 q0 = ep[0], q1 = ep[1], q2 = ep[2], q3 = ep[3];
    int   sA0 = rfl(q0.x), sB0 = rfl(q0.z);
    float wA0 = rflf(q0.y), wB0 = rflf(q0.w);
    int   sA1 = rfl(q1.x), sB1 = rfl(q1.z);
    float wA1 = rflf(q1.y), wB1 = rflf(q1.w);
    int   sA2 = rfl(q2.x), sB2 = rfl(q2.z);
    float wA2 = rflf(q2.y), wB2 = rflf(q2.w);
    int   sA3 = rfl(q3.x), sB3 = rfl(q3.z);
    float wA3 = rflf(q3.y), wB3 = rflf(q3.w);
    int g0 = half ? sB0 : sA0;  float w0 = half ? wB0 : wA0;
    int g1 = half ? sB1 : sA1;  float w1 = half ? wB1 : wA1;
    int g2 = half ? sB2 : sA2;  float w2 = half ? wB2 : wA2;
    int g3 = half ? sB3 : sA3;  float w3 = half ? wB3 : wA3;
    uint v0 = *(const uint*)&g[(size_t)g0 * sg + fl * 2];
    uint v1 = *(const uint*)&g[(size_t)g1 * sg + fl * 2];
    uint v2 = *(const uint*)&g[(size_t)g2 * sg + fl * 2];
    uint v3 = *(const uint*)&g[(size_t)g3 * sg + fl * 2];
    r0 += w0 * lo16(v0); r1 += w0 * hi16(v0);
    s0 += w1 * lo16(v1); s1 += w1 * hi16(v1);
    r0 += w2 * lo16(v2); r1 += w2 * hi16(v2);
    s0 += w3 * lo16(v3); s1 += w3 * hi16(v3);
  }
  for (; j < e1; j += 2) {       // 1-3 iters; padding has w=0
    uint4 q = *(const uint4*)(edges + j);
    int   sA = rfl(q.x), sB = rfl(q.z);
    float wA = rflf(q.y), wB = rflf(q.w);
    int gs = half ? sB : sA;  float ww = half ? wB : wA;
    uint v = *(const uint*)&g[(size_t)gs * sg + fl * 2];
    r0 += ww * lo16(v); r1 += ww * hi16(v);
  }
  r0 += s0; r1 += s1;
  r0 += __shfl_xor(r0, 32, 64);
  r1 += __shfl_xor(r1, 32, 64);
  r0 *= alpha; r1 *= alpha;
  if constexpr (NADD >= 1) {
    uint u = *(const uint*)&a1[(size_t)wv * sa1 + fl * 2];
    r0 += c1 * lo16(u); r1 += c1 * hi16(u);
  }
  if constexpr (NADD >= 2) {
    uint u = *(const uint*)&a2[(size_t)wv * sa2 + fl * 2];
    r0 += c2 * lo16(u); r1 += c2 * hi16(u);
  }
  if constexpr (RELUB) {
    float2 bv = ((const float2*)bias)[fl];
    r0 = fmaxf(r0 + bv.x, 0.f);
    r1 = fmaxf(r1 + bv.y, 0.f);
  }
  if (half == 0) {
    uint o = (uint)f2b(r0) | ((uint)f2b(r1) << 16);
    *(uint*)&out[(size_t)wv * so + fl * 2] = o;
  }
}

// ---------------- MFMA GEMM: C[n x Co](bf16) = A[n x Ci](bf16) @ Wt^T --------
// Wt is [Co][Ci] bf16 (B^T row-major). No LDS: B-frags from L1/L2,
// A-frags from global. Block = 4 waves; wave = 4 strips of 16 rows x 64 cols.

template<int Ci, int Co, bool BR>
__global__ __launch_bounds__(256) void gemm_mfma(const ushort* __restrict__ A,
    const ushort* __restrict__ Wt, const float* __restrict__ bias,
    ushort* __restrict__ C, int n)
{
  const int lane = threadIdx.x & 63;
  const int wid  = threadIdx.x >> 6;
  const int rb = blockIdx.x * 256;
  const int cb = blockIdx.y * 64;
  const int lr = lane & 15;            // row/col within fragment
  const int lk = (lane >> 4) << 3;     // k offset: 0,8,16,24
  f32x4 acc[4][4] = {};

  for (int kc = 0; kc < Ci; kc += 64) {
    bf16x8 bfrag[2][4];
    #pragma unroll
    for (int ks = 0; ks < 2; ++ks)
      #pragma unroll
      for (int nt = 0; nt < 4; ++nt)
        bfrag[ks][nt] = *(const bf16x8*)&Wt[(size_t)(cb + nt * 16 + lr) * Ci + kc + ks * 32 + lk];
    #pragma unroll
    for (int s = 0; s < 4; ++s) {
      const int row = rb + (wid * 4 + s) * 16 + lr;
      const ushort* ap = &A[(size_t)row * Ci + kc + lk];
      #pragma unroll
      for (int ks = 0; ks < 2; ++ks) {
        bf16x8 af = {};
        if (row < n) af = *(const bf16x8*)(ap + ks * 32);
        #pragma unroll
        for (int nt = 0; nt < 4; ++nt)
          acc[s][nt] = __builtin_amdgcn_mfma_f32_16x16x32_bf16(af, bfrag[ks][nt], acc[s][nt], 0, 0, 0);
      }
    }
  }

  #pragma unroll
  for (int s = 0; s < 4; ++s) {
    #pragma unroll
    for (int nt = 0; nt < 4; ++nt) {
      const int col = cb + nt * 16 + lr;
      #pragma unroll
      for (int r = 0; r < 4; ++r) {
        const int row = rb + (wid * 4 + s) * 16 + ((lane >> 4) << 2) + r;
        if (row < n) {
          float v = acc[s][nt][r];
          if constexpr (BR) v = fmaxf(v + bias[col], 0.f);
          C[(size_t)row * Co + col] = f2b(v);
        }
      }
    }
  }
}

// ---------------- pooling + head ----------------

__global__ __launch_bounds__(128) void pool_kernel(const ushort* __restrict__ h,
    const int* __restrict__ batch, float* __restrict__ pooled,
    float* __restrict__ gcnt, int n) {
  const int f = threadIdx.x;           // 0..127
  const int i0 = blockIdx.x * 64;
  const int iend = min(i0 + 64, n);
  int cur = batch[i0];
  float acc = 0.f;
  int run = 0;
  for (int i = i0; i < iend; ++i) {
    int b = batch[i];
    float v = b2f(h[(size_t)i * 128 + f]);
    if (b != cur) {
      atomicAdd(&pooled[cur * 128 + f], acc);
      if (f == 0) atomicAdd(&gcnt[cur], (float)run);
      acc = 0.f; run = 0; cur = b;
    }
    acc += v; run++;
  }
  atomicAdd(&pooled[cur * 128 + f], acc);
  if (f == 0) atomicAdd(&gcnt[cur], (float)run);
}

__global__ __launch_bounds__(128) void head_kernel(const float* __restrict__ pooled,
    const float* __restrict__ gcnt, const float* __restrict__ Wl,
    const float* __restrict__ bl, float* __restrict__ outp)
{
  int g = blockIdx.x, t = threadIdx.x;
  float denom = fmaxf(gcnt[g], 1.f);
  float p = pooled[g * 128 + t] / denom;
  __shared__ float s0[128], s1[128];
  s0[t] = p * Wl[t * 2 + 0];
  s1[t] = p * Wl[t * 2 + 1];
  __syncthreads();
  for (int off = 64; off > 0; off >>= 1) {
    if (t < off) { s0[t] += s0[t + off]; s1[t] += s1[t + off]; }
    __syncthreads();
  }
  if (t == 0) {
    float a = s0[0] + bl[0], b = s1[0] + bl[1];
    float m = fmaxf(a, b);
    float z = logf(expf(a - m) + expf(b - m)) + m;
    outp[g * 2 + 0] = a - z;
    outp[g * 2 + 1] = b - z;
  }
}

// ---------------- launch ----------------

extern "C" void kernel_launch(void* const* d_in, const int* in_sizes, int n_in,
                              void* d_out, int out_size, void* d_ws, size_t ws_size,
                              hipStream_t stream) {
  const float* x   = (const float*)d_in[0];
  const int*   ei  = (const int*)d_in[1];
  const float* ea  = (const float*)d_in[2];
  const int* batch = (const int*)d_in[3];
  const float* W1  = (const float*)d_in[4];
  const float* lb1 = (const float*)d_in[5];
  const float* W2  = (const float*)d_in[6];
  const float* lb2 = (const float*)d_in[7];
  const float* W3  = (const float*)d_in[8];
  const float* lb3 = (const float*)d_in[9];
  const float* Wl  = (const float*)d_in[10];
  const float* bl  = (const float*)d_in[11];
  const int* srcv = ei;
  const int* dstv = ei + EE;

  char* w = (char*)d_ws;
  auto alloc = [&](size_t bytes) -> char* {
    char* p = w; w += (bytes + 255) & ~(size_t)255; return p;
  };
  float* deg    = (float*)alloc((size_t)NN * 4);          // becomes dinv
  int*   rowptr = (int*)alloc((size_t)(NN + 1) * 4);
  int*   cnt    = (int*)alloc((size_t)NN * 4);            // becomes cursor
  int*   bsum   = (int*)alloc(256 * 4);
  uint2* edges  = (uint2*)alloc((size_t)(EE + NN) * 8);   // even-padded rows
  ushort* xb    = (ushort*)alloc((size_t)NN * 128 * 2);
  ushort* Acat  = (ushort*)alloc((size_t)NN * 320 * 2);   // a_k / Clenshaw / Tx_k
  ushort* Bcat  = (ushort*)alloc((size_t)NN * 320 * 2);   // layer2 blocks; later h3
  ushort* h1    = (ushort*)alloc((size_t)NN * 64 * 2);
  ushort* Wt1   = (ushort*)alloc((size_t)320 * 128 * 2);
  ushort* Wt2   = (ushort*)alloc((size_t)320 * 64 * 2);
  ushort* Wt3   = (ushort*)alloc((size_t)128 * 320 * 2);
  float* pooled = (float*)alloc((size_t)(GG * 128 + GG) * 4);
  float* gcnt   = pooled + GG * 128;
  int*   partial = (int*)Acat;     // scan scratch (Acat unused until GEMM1)
  ushort* h3 = Bcat;               // layer-3 output reuses Bcat

  hipMemsetAsync(deg, 0, (size_t)NN * 4, stream);
  hipMemsetAsync(cnt, 0, (size_t)NN * 4, stream);
  hipMemsetAsync(pooled, 0, (size_t)(GG * 128 + GG) * 4, stream);
  hipMemsetAsync(edges, 0, (size_t)(EE + NN) * 8, stream);  // padding slots w=0

  deg_hist_kernel<<<(EE + 255) / 256, 256, 0, stream>>>(srcv, dstv, ea, deg, cnt, EE);
  dinv_kernel<<<(NN + 255) / 256, 256, 0, stream>>>(deg, NN);
  const int nb = (NN + 255) / 256;  // 196
  scan1<<<nb, 256, 0, stream>>>(cnt, partial, bsum, NN);
  scan2<<<1, 256, 0, stream>>>(bsum, nb);
  scan3<<<nb, 256, 0, stream>>>(partial, bsum, rowptr, NN);
  cursor_init<<<nb, 256, 0, stream>>>(rowptr, cnt, NN);
  scatter_kernel<<<(EE + 255) / 256, 256, 0, stream>>>(srcv, dstv, ea, deg, cnt, edges, EE);

  cvt_x<<<(NN * 128 / 4 + 255) / 256, 256, 0, stream>>>(x, xb, NN * 128 / 4);
  cvt_w<<<(320 * 128 + 320 * 64 + 128 * 320 + 255) / 256, 256, 0, stream>>>(
      W1, W2, W3, Wt1, Wt2, Wt3);

  const int PG = (NN + 3) / 4;       // prop blocks (4 waves each)
  const int GX = (NN + 255) / 256;   // gemm row-blocks

  ushort* A0 = Acat + 0 * 64;  ushort* A1 = Acat + 1 * 64;  ushort* A2 = Acat + 2 * 64;
  ushort* A3 = Acat + 3 * 64;  ushort* A4 = Acat + 4 * 64;
  ushort* B0 = Bcat + 0 * 64;  ushort* B1 = Bcat + 1 * 64;  ushort* B2 = Bcat + 2 * 64;
  ushort* B3 = Bcat + 3 * 64;  ushort* B4 = Bcat + 4 * 64;
  const int S = 320;

  // ---- Layer 1 (Clenshaw): a_k = x @ W1_k  -> Acat[50000][320] ----
  gemm_mfma<128, 320, false><<<dim3(GX, 5), 256, 0, stream>>>(xb, Wt1, nullptr, Acat, NN);
  prop_kernel<1, false><<<PG, 256, 0, stream>>>(rowptr, edges, A4, S, A3, S, 1.f,
      nullptr, 0, 0.f, nullptr, A3, S, NN, 2.f);
  prop_kernel<2, false><<<PG, 256, 0, stream>>>(rowptr, edges, A3, S, A2, S, 1.f,
      A4, S, -1.f, nullptr, A2, S, NN, 2.f);
  prop_kernel<2, false><<<PG, 256, 0, stream>>>(rowptr, edges, A2, S, A1, S, 1.f,
      A3, S, -1.f, nullptr, A1, S, NN, 2.f);
  prop_kernel<2, true><<<PG, 256, 0, stream>>>(rowptr, edges, A1, S, A0, S, 1.f,
      A2, S, -1.f, lb1, h1, 64, NN, 1.f);

  // ---- Layer 2 (Clenshaw): a_k = h1 @ W2_k -> Bcat ----
  gemm_mfma<64, 320, false><<<dim3(GX, 5), 256, 0, stream>>>(h1, Wt2, nullptr, Bcat, NN);
  prop_kernel<1, false><<<PG, 256, 0, stream>>>(rowptr, edges, B4, S, B3, S, 1.f,
      nullptr, 0, 0.f, nullptr, B3, S, NN, 2.f);
  prop_kernel<2, false><<<PG, 256, 0, stream>>>(rowptr, edges, B3, S, B2, S, 1.f,
      B4, S, -1.f, nullptr, B2, S, NN, 2.f);
  prop_kernel<2, false><<<PG, 256, 0, stream>>>(rowptr, edges, B2, S, B1, S, 1.f,
      B3, S, -1.f, nullptr, B1, S, NN, 2.f);
  // h2 -> Acat block 0 (Tx0), strided
  prop_kernel<2, true><<<PG, 256, 0, stream>>>(rowptr, edges, B1, S, B0, S, 1.f,
      B2, S, -1.f, lb2, A0, S, NN, 1.f);

  // ---- Layer 3 (forward recursion, Tx_k in Acat blocks) ----
  prop_kernel<0, false><<<PG, 256, 0, stream>>>(rowptr, edges, A0, S, nullptr, 0, 0.f,
      nullptr, 0, 0.f, nullptr, A1, S, NN, 1.f);
  prop_kernel<1, false><<<PG, 256, 0, stream>>>(rowptr, edges, A1, S, A0, S, -1.f,
      nullptr, 0, 0.f, nullptr, A2, S, NN, 2.f);
  prop_kernel<1, false><<<PG, 256, 0, stream>>>(rowptr, edges, A2, S, A1, S, -1.f,
      nullptr, 0, 0.f, nullptr, A3, S, NN, 2.f);
  prop_kernel<1, false><<<PG, 256, 0, stream>>>(rowptr, edges, A3, S, A2, S, -1.f,
      nullptr, 0, 0.f, nullptr, A4, S, NN, 2.f);
  // h3 = relu([Tx0|..|Tx4] @ W3stack + b3)
  gemm_mfma<320, 128, true><<<dim3(GX, 2), 256, 0, stream>>>(Acat, Wt3, lb3, h3, NN);

  // ---- pool + head ----
  pool_kernel<<<(NN + 63) / 64, 128, 0, stream>>>(h3, batch, pooled, gcnt, NN);
  head_kernel<<<GG, 128, 0, stream>>>(pooled, gcnt, Wl, bl, (float*)d_out);
}

// Round 6
// 714.557 us; speedup vs baseline: 1.2900x; 1.0380x over previous
//
#include <hip/hip_runtime.h>
#include <hip/hip_bf16.h>

#define NN 50000
#define EE 1600000
#define GG 500

typedef __bf16 bf16x8 __attribute__((ext_vector_type(8)));
typedef float  f32x4  __attribute__((ext_vector_type(4)));

__device__ __forceinline__ float b2f(ushort u) {
  return __uint_as_float(((unsigned)u) << 16);
}
__device__ __forceinline__ ushort f2b(float f) {
  unsigned u = __float_as_uint(f);
  unsigned r = (u + 0x7fff + ((u >> 16) & 1)) >> 16;   // RNE
  return (ushort)r;
}
__device__ __forceinline__ float lo16(uint v) { return __uint_as_float(v << 16); }
__device__ __forceinline__ float hi16(uint v) { return __uint_as_float(v & 0xffff0000u); }
__device__ __forceinline__ int rfl(uint v) { return __builtin_amdgcn_readfirstlane((int)v); }
__device__ __forceinline__ float rflf(uint v) {
  return __uint_as_float((unsigned)__builtin_amdgcn_readfirstlane((int)v));
}

// ---------------- graph preprocessing ----------------

// deg[src] += ea (fire-and-forget); rank[i] = running count of dst (returning)
__global__ void deg_hist_kernel(const int* __restrict__ src, const int* __restrict__ dst,
                                const float* __restrict__ ea, float* __restrict__ deg,
                                int* __restrict__ cnt, int* __restrict__ rank, int e) {
  int i = blockIdx.x * blockDim.x + threadIdx.x;
  if (i < e) {
    atomicAdd(&deg[src[i]], ea[i]);
    rank[i] = atomicAdd(&cnt[dst[i]], 1);
  }
}

__global__ void dinv_kernel(float* __restrict__ deg, int n) {
  int i = blockIdx.x * blockDim.x + threadIdx.x;
  if (i < n) { float d = deg[i]; deg[i] = (d > 0.f) ? (1.0f / sqrtf(d)) : 0.f; }
}

// scan over EVEN-PADDED counts: row i gets ceil(cnt/2)*2 slots (16B-aligned rows)
__global__ void scan1(const int* __restrict__ cnt, int* __restrict__ partial,
                      int* __restrict__ bsum, int n) {
  __shared__ int s[256];
  int t = threadIdx.x, i = blockIdx.x * 256 + t;
  int v = (i < n) ? ((cnt[i] + 1) & ~1) : 0;
  s[t] = v; __syncthreads();
  for (int off = 1; off < 256; off <<= 1) {
    int xv = (t >= off) ? s[t - off] : 0;
    __syncthreads(); s[t] += xv; __syncthreads();
  }
  if (i < n) partial[i] = s[t];
  if (t == 255) bsum[blockIdx.x] = s[255];
}

__global__ void scan2(int* __restrict__ bsum, int nb) {
  __shared__ int s[256];
  int t = threadIdx.x;
  int v = (t < nb) ? bsum[t] : 0;
  s[t] = v; __syncthreads();
  for (int off = 1; off < 256; off <<= 1) {
    int xv = (t >= off) ? s[t - off] : 0;
    __syncthreads(); s[t] += xv; __syncthreads();
  }
  if (t < nb) bsum[t] = s[t];
}

__global__ void scan3(const int* __restrict__ partial, const int* __restrict__ bsum,
                      int* __restrict__ rowptr, int n) {
  int i = blockIdx.x * 256 + threadIdx.x;
  if (i < n) {
    int off = (blockIdx.x > 0) ? bsum[blockIdx.x - 1] : 0;
    rowptr[i + 1] = partial[i] + off;
    if (i == 0) rowptr[0] = 0;
  }
}

// atomic-free: pos = rowptr[d] + rank (rank captured during histogram)
__global__ void scatter_kernel(const int* __restrict__ src, const int* __restrict__ dst,
                               const float* __restrict__ ea, const float* __restrict__ dinv,
                               const int* __restrict__ rowptr, const int* __restrict__ rank,
                               uint2* __restrict__ edges, int e) {
  int i = blockIdx.x * blockDim.x + threadIdx.x;
  if (i < e) {
    int s = src[i], d = dst[i];
    float w = -dinv[s] * ea[i] * dinv[d];
    edges[rowptr[d] + rank[i]] = make_uint2((unsigned)s, __float_as_uint(w));
  }
}

// write the single {0,0} filler slot for odd-degree rows (replaces 12.8MB memset)
__global__ void pad_kernel(const int* __restrict__ rowptr, const int* __restrict__ cnt,
                           uint2* __restrict__ edges, int n) {
  int i = blockIdx.x * 256 + threadIdx.x;
  if (i < n && (cnt[i] & 1)) edges[rowptr[i] + cnt[i]] = make_uint2(0u, 0u);
}

// ---------------- dtype conversions ----------------

__global__ void cvt_x(const float* __restrict__ x, ushort* __restrict__ xb, int n4) {
  int i = blockIdx.x * 256 + threadIdx.x;
  if (i < n4) {
    float4 v = ((const float4*)x)[i];
    ushort4 o;
    o.x = f2b(v.x); o.y = f2b(v.y); o.z = f2b(v.z); o.w = f2b(v.w);
    ((ushort4*)xb)[i] = o;
  }
}

// Wt1[320][128] = W1[j>>6][k][j&63]; Wt2[320][64]; Wt3[128][320] = W3stack^T
__global__ void cvt_w(const float* __restrict__ W1, const float* __restrict__ W2,
                      const float* __restrict__ W3, ushort* __restrict__ Wt1,
                      ushort* __restrict__ Wt2, ushort* __restrict__ Wt3) {
  int i = blockIdx.x * 256 + threadIdx.x;
  if (i < 320 * 128) {
    int j = i / 128, k = i % 128;
    Wt1[i] = f2b(W1[((size_t)(j >> 6) * 128 + k) * 64 + (j & 63)]);
  } else if (i < 320 * 128 + 320 * 64) {
    int t = i - 320 * 128; int j = t / 64, k = t % 64;
    Wt2[t] = f2b(W2[((size_t)(j >> 6) * 64 + k) * 64 + (j & 63)]);
  } else if (i < 320 * 128 + 320 * 64 + 128 * 320) {
    int t = i - 320 * 128 - 320 * 64; int j = t / 320, k = t % 320;
    Wt3[t] = f2b(W3[(size_t)k * 128 + j]);
  }
}

// ---------------- sparse propagation V3 ----------------
// Wave = 1 dst node. Edges scalar-broadcast (SGPR); lanes 0-31 gather even
// edges' rows, lanes 32-63 odd edges' rows, 4B (2 bf16 feats) per lane.
// Rows even-padded with {src=0,w=0} so uint4 edge loads are 16B-aligned and
// no validity branches are needed. Halves combined once via shfl_xor(32).
// out = alpha * prop(g) + c1*a1 + c2*a2   [+ bias, relu]

template<int NADD, bool RELUB>
__global__ __launch_bounds__(256) void prop_kernel(
    const int* __restrict__ rowptr, const uint2* __restrict__ edges,
    const ushort* __restrict__ g, int sg,
    const ushort* __restrict__ a1, int sa1, float c1,
    const ushort* __restrict__ a2, int sa2, float c2,
    const float* __restrict__ bias,
    ushort* __restrict__ out, int so, int n, float alpha)
{
  int wv = blockIdx.x * 4 + (threadIdx.x >> 6);
  wv = __builtin_amdgcn_readfirstlane(wv);
  const int lane = threadIdx.x & 63;
  const int half = lane >> 5;
  const int fl   = lane & 31;
  if (wv >= n) return;
  const int e0 = __builtin_amdgcn_readfirstlane(rowptr[wv]);
  const int e1 = __builtin_amdgcn_readfirstlane(rowptr[wv + 1]);

  float r0 = 0.f, r1 = 0.f, s0 = 0.f, s1 = 0.f;
  int j = e0;
  for (; j + 8 <= e1; j += 8) {
    const uint4* ep = (const uint4*)(edges + j);   // 16B-aligned (rows even-padded)
    uint4 q0 = ep[0], q1 = ep[1], q2 = ep[2], q3 = ep[3];
    int   sA0 = rfl(q0.x), sB0 = rfl(q0.z);
    float wA0 = rflf(q0.y), wB0 = rflf(q0.w);
    int   sA1 = rfl(q1.x), sB1 = rfl(q1.z);
    float wA1 = rflf(q1.y), wB1 = rflf(q1.w);
    int   sA2 = rfl(q2.x), sB2 = rfl(q2.z);
    float wA2 = rflf(q2.y), wB2 = rflf(q2.w);
    int   sA3 = rfl(q3.x), sB3 = rfl(q3.z);
    float wA3 = rflf(q3.y), wB3 = rflf(q3.w);
    int g0 = half ? sB0 : sA0;  float w0 = half ? wB0 : wA0;
    int g1 = half ? sB1 : sA1;  float w1 = half ? wB1 : wA1;
    int g2 = half ? sB2 : sA2;  float w2 = half ? wB2 : wA2;
    int g3 = half ? sB3 : sA3;  float w3 = half ? wB3 : wA3;
    uint v0 = *(const uint*)&g[(size_t)g0 * sg + fl * 2];
    uint v1 = *(const uint*)&g[(size_t)g1 * sg + fl * 2];
    uint v2 = *(const uint*)&g[(size_t)g2 * sg + fl * 2];
    uint v3 = *(const uint*)&g[(size_t)g3 * sg + fl * 2];
    r0 += w0 * lo16(v0); r1 += w0 * hi16(v0);
    s0 += w1 * lo16(v1); s1 += w1 * hi16(v1);
    r0 += w2 * lo16(v2); r1 += w2 * hi16(v2);
    s0 += w3 * lo16(v3); s1 += w3 * hi16(v3);
  }
  for (; j < e1; j += 2) {       // 1-3 iters; padding has w=0
    uint4 q = *(const uint4*)(edges + j);
    int   sA = rfl(q.x), sB = rfl(q.z);
    float wA = rflf(q.y), wB = rflf(q.w);
    int gs = half ? sB : sA;  float ww = half ? wB : wA;
    uint v = *(const uint*)&g[(size_t)gs * sg + fl * 2];
    r0 += ww * lo16(v); r1 += ww * hi16(v);
  }
  r0 += s0; r1 += s1;
  r0 += __shfl_xor(r0, 32, 64);
  r1 += __shfl_xor(r1, 32, 64);
  r0 *= alpha; r1 *= alpha;
  if constexpr (NADD >= 1) {
    uint u = *(const uint*)&a1[(size_t)wv * sa1 + fl * 2];
    r0 += c1 * lo16(u); r1 += c1 * hi16(u);
  }
  if constexpr (NADD >= 2) {
    uint u = *(const uint*)&a2[(size_t)wv * sa2 + fl * 2];
    r0 += c2 * lo16(u); r1 += c2 * hi16(u);
  }
  if constexpr (RELUB) {
    float2 bv = ((const float2*)bias)[fl];
    r0 = fmaxf(r0 + bv.x, 0.f);
    r1 = fmaxf(r1 + bv.y, 0.f);
  }
  if (half == 0) {
    uint o = (uint)f2b(r0) | ((uint)f2b(r1) << 16);
    *(uint*)&out[(size_t)wv * so + fl * 2] = o;
  }
}

// ---------------- MFMA GEMM: C[n x Co](bf16) = A[n x Ci](bf16) @ Wt^T --------
// Wt is [Co][Ci] bf16 (B^T row-major). No LDS: B-frags from L1/L2,
// A-frags from global. Block = 4 waves; wave = 4 strips of 16 rows x 64 cols.

template<int Ci, int Co, bool BR>
__global__ __launch_bounds__(256) void gemm_mfma(const ushort* __restrict__ A,
    const ushort* __restrict__ Wt, const float* __restrict__ bias,
    ushort* __restrict__ C, int n)
{
  const int lane = threadIdx.x & 63;
  const int wid  = threadIdx.x >> 6;
  const int rb = blockIdx.x * 256;
  const int cb = blockIdx.y * 64;
  const int lr = lane & 15;            // row/col within fragment
  const int lk = (lane >> 4) << 3;     // k offset: 0,8,16,24
  f32x4 acc[4][4] = {};

  for (int kc = 0; kc < Ci; kc += 64) {
    bf16x8 bfrag[2][4];
    #pragma unroll
    for (int ks = 0; ks < 2; ++ks)
      #pragma unroll
      for (int nt = 0; nt < 4; ++nt)
        bfrag[ks][nt] = *(const bf16x8*)&Wt[(size_t)(cb + nt * 16 + lr) * Ci + kc + ks * 32 + lk];
    #pragma unroll
    for (int s = 0; s < 4; ++s) {
      const int row = rb + (wid * 4 + s) * 16 + lr;
      const ushort* ap = &A[(size_t)row * Ci + kc + lk];
      #pragma unroll
      for (int ks = 0; ks < 2; ++ks) {
        bf16x8 af = {};
        if (row < n) af = *(const bf16x8*)(ap + ks * 32);
        #pragma unroll
        for (int nt = 0; nt < 4; ++nt)
          acc[s][nt] = __builtin_amdgcn_mfma_f32_16x16x32_bf16(af, bfrag[ks][nt], acc[s][nt], 0, 0, 0);
      }
    }
  }

  #pragma unroll
  for (int s = 0; s < 4; ++s) {
    #pragma unroll
    for (int nt = 0; nt < 4; ++nt) {
      const int col = cb + nt * 16 + lr;
      #pragma unroll
      for (int r = 0; r < 4; ++r) {
        const int row = rb + (wid * 4 + s) * 16 + ((lane >> 4) << 2) + r;
        if (row < n) {
          float v = acc[s][nt][r];
          if constexpr (BR) v = fmaxf(v + bias[col], 0.f);
          C[(size_t)row * Co + col] = f2b(v);
        }
      }
    }
  }
}

// ---------------- pooling + head ----------------

__global__ __launch_bounds__(128) void pool_kernel(const ushort* __restrict__ h,
    const int* __restrict__ batch, float* __restrict__ pooled,
    float* __restrict__ gcnt, int n) {
  const int f = threadIdx.x;           // 0..127
  const int i0 = blockIdx.x * 64;
  const int iend = min(i0 + 64, n);
  int cur = batch[i0];
  float acc = 0.f;
  int run = 0;
  for (int i = i0; i < iend; ++i) {
    int b = batch[i];
    float v = b2f(h[(size_t)i * 128 + f]);
    if (b != cur) {
      atomicAdd(&pooled[cur * 128 + f], acc);
      if (f == 0) atomicAdd(&gcnt[cur], (float)run);
      acc = 0.f; run = 0; cur = b;
    }
    acc += v; run++;
  }
  atomicAdd(&pooled[cur * 128 + f], acc);
  if (f == 0) atomicAdd(&gcnt[cur], (float)run);
}

__global__ __launch_bounds__(128) void head_kernel(const float* __restrict__ pooled,
    const float* __restrict__ gcnt, const float* __restrict__ Wl,
    const float* __restrict__ bl, float* __restrict__ outp)
{
  int g = blockIdx.x, t = threadIdx.x;
  float denom = fmaxf(gcnt[g], 1.f);
  float p = pooled[g * 128 + t] / denom;
  __shared__ float s0[128], s1[128];
  s0[t] = p * Wl[t * 2 + 0];
  s1[t] = p * Wl[t * 2 + 1];
  __syncthreads();
  for (int off = 64; off > 0; off >>= 1) {
    if (t < off) { s0[t] += s0[t + off]; s1[t] += s1[t + off]; }
    __syncthreads();
  }
  if (t == 0) {
    float a = s0[0] + bl[0], b = s1[0] + bl[1];
    float m = fmaxf(a, b);
    float z = logf(expf(a - m) + expf(b - m)) + m;
    outp[g * 2 + 0] = a - z;
    outp[g * 2 + 1] = b - z;
  }
}

// ---------------- launch ----------------

extern "C" void kernel_launch(void* const* d_in, const int* in_sizes, int n_in,
                              void* d_out, int out_size, void* d_ws, size_t ws_size,
                              hipStream_t stream) {
  const float* x   = (const float*)d_in[0];
  const int*   ei  = (const int*)d_in[1];
  const float* ea  = (const float*)d_in[2];
  const int* batch = (const int*)d_in[3];
  const float* W1  = (const float*)d_in[4];
  const float* lb1 = (const float*)d_in[5];
  const float* W2  = (const float*)d_in[6];
  const float* lb2 = (const float*)d_in[7];
  const float* W3  = (const float*)d_in[8];
  const float* lb3 = (const float*)d_in[9];
  const float* Wl  = (const float*)d_in[10];
  const float* bl  = (const float*)d_in[11];
  const int* srcv = ei;
  const int* dstv = ei + EE;

  char* w = (char*)d_ws;
  auto alloc = [&](size_t bytes) -> char* {
    char* p = w; w += (bytes + 255) & ~(size_t)255; return p;
  };
  float* deg    = (float*)alloc((size_t)NN * 4);          // becomes dinv
  int*   rowptr = (int*)alloc((size_t)(NN + 1) * 4);
  int*   cnt    = (int*)alloc((size_t)NN * 4);
  int*   bsum   = (int*)alloc(256 * 4);
  int*   rank   = (int*)alloc((size_t)EE * 4);
  uint2* edges  = (uint2*)alloc((size_t)(EE + NN) * 8);   // even-padded rows
  ushort* xb    = (ushort*)alloc((size_t)NN * 128 * 2);
  ushort* Acat  = (ushort*)alloc((size_t)NN * 320 * 2);   // a_k / Clenshaw / Tx_k
  ushort* Bcat  = (ushort*)alloc((size_t)NN * 320 * 2);   // layer2 blocks; later h3
  ushort* h1    = (ushort*)alloc((size_t)NN * 64 * 2);
  ushort* Wt1   = (ushort*)alloc((size_t)320 * 128 * 2);
  ushort* Wt2   = (ushort*)alloc((size_t)320 * 64 * 2);
  ushort* Wt3   = (ushort*)alloc((size_t)128 * 320 * 2);
  float* pooled = (float*)alloc((size_t)(GG * 128 + GG) * 4);
  float* gcnt   = pooled + GG * 128;
  int*   partial = (int*)Acat;     // scan scratch (Acat unused until GEMM1)
  ushort* h3 = Bcat;               // layer-3 output reuses Bcat

  hipMemsetAsync(deg, 0, (size_t)NN * 4, stream);
  hipMemsetAsync(cnt, 0, (size_t)NN * 4, stream);
  hipMemsetAsync(pooled, 0, (size_t)(GG * 128 + GG) * 4, stream);

  deg_hist_kernel<<<(EE + 255) / 256, 256, 0, stream>>>(srcv, dstv, ea, deg, cnt, rank, EE);
  dinv_kernel<<<(NN + 255) / 256, 256, 0, stream>>>(deg, NN);
  const int nb = (NN + 255) / 256;  // 196
  scan1<<<nb, 256, 0, stream>>>(cnt, partial, bsum, NN);
  scan2<<<1, 256, 0, stream>>>(bsum, nb);
  scan3<<<nb, 256, 0, stream>>>(partial, bsum, rowptr, NN);
  scatter_kernel<<<(EE + 255) / 256, 256, 0, stream>>>(srcv, dstv, ea, deg, rowptr, rank,
                                                       edges, EE);
  pad_kernel<<<nb, 256, 0, stream>>>(rowptr, cnt, edges, NN);

  cvt_x<<<(NN * 128 / 4 + 255) / 256, 256, 0, stream>>>(x, xb, NN * 128 / 4);
  cvt_w<<<(320 * 128 + 320 * 64 + 128 * 320 + 255) / 256, 256, 0, stream>>>(
      W1, W2, W3, Wt1, Wt2, Wt3);

  const int PG = (NN + 3) / 4;       // prop blocks (4 waves each)
  const int GX = (NN + 255) / 256;   // gemm row-blocks

  ushort* A0 = Acat + 0 * 64;  ushort* A1 = Acat + 1 * 64;  ushort* A2 = Acat + 2 * 64;
  ushort* A3 = Acat + 3 * 64;  ushort* A4 = Acat + 4 * 64;
  ushort* B0 = Bcat + 0 * 64;  ushort* B1 = Bcat + 1 * 64;  ushort* B2 = Bcat + 2 * 64;
  ushort* B3 = Bcat + 3 * 64;  ushort* B4 = Bcat + 4 * 64;
  const int S = 320;

  // ---- Layer 1 (Clenshaw): a_k = x @ W1_k  -> Acat[50000][320] ----
  gemm_mfma<128, 320, false><<<dim3(GX, 5), 256, 0, stream>>>(xb, Wt1, nullptr, Acat, NN);
  prop_kernel<1, false><<<PG, 256, 0, stream>>>(rowptr, edges, A4, S, A3, S, 1.f,
      nullptr, 0, 0.f, nullptr, A3, S, NN, 2.f);
  prop_kernel<2, false><<<PG, 256, 0, stream>>>(rowptr, edges, A3, S, A2, S, 1.f,
      A4, S, -1.f, nullptr, A2, S, NN, 2.f);
  prop_kernel<2, false><<<PG, 256, 0, stream>>>(rowptr, edges, A2, S, A1, S, 1.f,
      A3, S, -1.f, nullptr, A1, S, NN, 2.f);
  prop_kernel<2, true><<<PG, 256, 0, stream>>>(rowptr, edges, A1, S, A0, S, 1.f,
      A2, S, -1.f, lb1, h1, 64, NN, 1.f);

  // ---- Layer 2 (Clenshaw): a_k = h1 @ W2_k -> Bcat ----
  gemm_mfma<64, 320, false><<<dim3(GX, 5), 256, 0, stream>>>(h1, Wt2, nullptr, Bcat, NN);
  prop_kernel<1, false><<<PG, 256, 0, stream>>>(rowptr, edges, B4, S, B3, S, 1.f,
      nullptr, 0, 0.f, nullptr, B3, S, NN, 2.f);
  prop_kernel<2, false><<<PG, 256, 0, stream>>>(rowptr, edges, B3, S, B2, S, 1.f,
      B4, S, -1.f, nullptr, B2, S, NN, 2.f);
  prop_kernel<2, false><<<PG, 256, 0, stream>>>(rowptr, edges, B2, S, B1, S, 1.f,
      B3, S, -1.f, nullptr, B1, S, NN, 2.f);
  // h2 -> Acat block 0 (Tx0), strided
  prop_kernel<2, true><<<PG, 256, 0, stream>>>(rowptr, edges, B1, S, B0, S, 1.f,
      B2, S, -1.f, lb2, A0, S, NN, 1.f);

  // ---- Layer 3 (forward recursion, Tx_k in Acat blocks) ----
  prop_kernel<0, false><<<PG, 256, 0, stream>>>(rowptr, edges, A0, S, nullptr, 0, 0.f,
      nullptr, 0, 0.f, nullptr, A1, S, NN, 1.f);
  prop_kernel<1, false><<<PG, 256, 0, stream>>>(rowptr, edges, A1, S, A0, S, -1.f,
      nullptr, 0, 0.f, nullptr, A2, S, NN, 2.f);
  prop_kernel<1, false><<<PG, 256, 0, stream>>>(rowptr, edges, A2, S, A1, S, -1.f,
      nullptr, 0, 0.f, nullptr, A3, S, NN, 2.f);
  prop_kernel<1, false><<<PG, 256, 0, stream>>>(rowptr, edges, A3, S, A2, S, -1.f,
      nullptr, 0, 0.f, nullptr, A4, S, NN, 2.f);
  // h3 = relu([Tx0|..|Tx4] @ W3stack + b3)
  gemm_mfma<320, 128, true><<<dim3(GX, 2), 256, 0, stream>>>(Acat, Wt3, lb3, h3, NN);

  // ---- pool + head ----
  pool_kernel<<<(NN + 63) / 64, 128, 0, stream>>>(h3, batch, pooled, gcnt, NN);
  head_kernel<<<GG, 128, 0, stream>>>(pooled, gcnt, Wl, bl, (float*)d_out);
}

// Round 7
// 667.434 us; speedup vs baseline: 1.3811x; 1.0706x over previous
//
#include <hip/hip_runtime.h>
#include <hip/hip_bf16.h>

#define NN 50000
#define EE 1600000
#define GG 500

typedef __bf16 bf16x8 __attribute__((ext_vector_type(8)));
typedef float  f32x4  __attribute__((ext_vector_type(4)));

__device__ __forceinline__ float b2f(ushort u) {
  return __uint_as_float(((unsigned)u) << 16);
}
__device__ __forceinline__ ushort f2b(float f) {
  unsigned u = __float_as_uint(f);
  unsigned r = (u + 0x7fff + ((u >> 16) & 1)) >> 16;   // RNE
  return (ushort)r;
}
__device__ __forceinline__ float lo16(uint v) { return __uint_as_float(v << 16); }
__device__ __forceinline__ float hi16(uint v) { return __uint_as_float(v & 0xffff0000u); }

// ---------------- graph preprocessing ----------------

// deg[src] += ea (fire-and-forget); rank[i] = running count of dst (returning)
__global__ void deg_hist_kernel(const int* __restrict__ src, const int* __restrict__ dst,
                                const float* __restrict__ ea, float* __restrict__ deg,
                                int* __restrict__ cnt, int* __restrict__ rank, int e) {
  int i = blockIdx.x * blockDim.x + threadIdx.x;
  if (i < e) {
    atomicAdd(&deg[src[i]], ea[i]);
    rank[i] = atomicAdd(&cnt[dst[i]], 1);
  }
}

__global__ void dinv_kernel(float* __restrict__ deg, int n) {
  int i = blockIdx.x * blockDim.x + threadIdx.x;
  if (i < n) { float d = deg[i]; deg[i] = (d > 0.f) ? (1.0f / sqrtf(d)) : 0.f; }
}

// scan over 8-PADDED counts: row i gets ceil(cnt/8)*8 slots (64B-aligned rows)
__global__ void scan1(const int* __restrict__ cnt, int* __restrict__ partial,
                      int* __restrict__ bsum, int n) {
  __shared__ int s[256];
  int t = threadIdx.x, i = blockIdx.x * 256 + t;
  int v = (i < n) ? ((cnt[i] + 7) & ~7) : 0;
  s[t] = v; __syncthreads();
  for (int off = 1; off < 256; off <<= 1) {
    int xv = (t >= off) ? s[t - off] : 0;
    __syncthreads(); s[t] += xv; __syncthreads();
  }
  if (i < n) partial[i] = s[t];
  if (t == 255) bsum[blockIdx.x] = s[255];
}

__global__ void scan2(int* __restrict__ bsum, int nb) {
  __shared__ int s[256];
  int t = threadIdx.x;
  int v = (t < nb) ? bsum[t] : 0;
  s[t] = v; __syncthreads();
  for (int off = 1; off < 256; off <<= 1) {
    int xv = (t >= off) ? s[t - off] : 0;
    __syncthreads(); s[t] += xv; __syncthreads();
  }
  if (t < nb) bsum[t] = s[t];
}

__global__ void scan3(const int* __restrict__ partial, const int* __restrict__ bsum,
                      int* __restrict__ rowptr, int n) {
  int i = blockIdx.x * 256 + threadIdx.x;
  if (i < n) {
    int off = (blockIdx.x > 0) ? bsum[blockIdx.x - 1] : 0;
    rowptr[i + 1] = partial[i] + off;
    if (i == 0) rowptr[0] = 0;
  }
}

// atomic-free: pos = rowptr[d] + rank (rank captured during histogram)
__global__ void scatter_kernel(const int* __restrict__ src, const int* __restrict__ dst,
                               const float* __restrict__ ea, const float* __restrict__ dinv,
                               const int* __restrict__ rowptr, const int* __restrict__ rank,
                               uint2* __restrict__ edges, int e) {
  int i = blockIdx.x * blockDim.x + threadIdx.x;
  if (i < e) {
    int s = src[i], d = dst[i];
    float w = -dinv[s] * ea[i] * dinv[d];
    edges[rowptr[d] + rank[i]] = make_uint2((unsigned)s, __float_as_uint(w));
  }
}

// fill {src=0,w=0} filler slots for rows padded to a multiple of 8
__global__ void pad_kernel(const int* __restrict__ rowptr, const int* __restrict__ cnt,
                           uint2* __restrict__ edges, int n) {
  int i = blockIdx.x * 256 + threadIdx.x;
  if (i < n) {
    int c = cnt[i], p = (c + 7) & ~7, base = rowptr[i];
    for (int q = c; q < p; ++q) edges[base + q] = make_uint2(0u, 0u);
  }
}

// ---------------- dtype conversions ----------------

__global__ void cvt_x(const float* __restrict__ x, ushort* __restrict__ xb, int n4) {
  int i = blockIdx.x * 256 + threadIdx.x;
  if (i < n4) {
    float4 v = ((const float4*)x)[i];
    ushort4 o;
    o.x = f2b(v.x); o.y = f2b(v.y); o.z = f2b(v.z); o.w = f2b(v.w);
    ((ushort4*)xb)[i] = o;
  }
}

// Wt1[320][128] = W1[j>>6][k][j&63]; Wt2[320][64]; Wt3[128][320] = W3stack^T
__global__ void cvt_w(const float* __restrict__ W1, const float* __restrict__ W2,
                      const float* __restrict__ W3, ushort* __restrict__ Wt1,
                      ushort* __restrict__ Wt2, ushort* __restrict__ Wt3) {
  int i = blockIdx.x * 256 + threadIdx.x;
  if (i < 320 * 128) {
    int j = i / 128, k = i % 128;
    Wt1[i] = f2b(W1[((size_t)(j >> 6) * 128 + k) * 64 + (j & 63)]);
  } else if (i < 320 * 128 + 320 * 64) {
    int t = i - 320 * 128; int j = t / 64, k = t % 64;
    Wt2[t] = f2b(W2[((size_t)(j >> 6) * 64 + k) * 64 + (j & 63)]);
  } else if (i < 320 * 128 + 320 * 64 + 128 * 320) {
    int t = i - 320 * 128 - 320 * 64; int j = t / 320, k = t % 320;
    Wt3[t] = f2b(W3[(size_t)k * 128 + j]);
  }
}

// ---------------- sparse propagation V4 ----------------
// Wave = 1 dst node. 8 edges per gather instruction: lane = (grp=lane>>3,
// sub=lane&7); lane loads edge meta edges[j+grp] (per-lane, no broadcast
// needed) and gathers 16B of src row (sub*8 feats). Rows padded to %8 with
// {src=0,w=0} fillers. Feature partials reduced across the 8 groups with a
// 3-step shfl_xor butterfly once per node.
// out = alpha * prop(g) + c1*a1 + c2*a2   [+ bias, relu]

template<int NADD, bool RELUB>
__global__ __launch_bounds__(256) void prop_kernel(
    const int* __restrict__ rowptr, const uint2* __restrict__ edges,
    const ushort* __restrict__ g, int sg,
    const ushort* __restrict__ a1, int sa1, float c1,
    const ushort* __restrict__ a2, int sa2, float c2,
    const float* __restrict__ bias,
    ushort* __restrict__ out, int so, int n, float alpha)
{
  int wv = blockIdx.x * 4 + (threadIdx.x >> 6);
  wv = __builtin_amdgcn_readfirstlane(wv);
  const int lane = threadIdx.x & 63;
  const int grp = lane >> 3;   // edge within 8-pack
  const int sub = lane & 7;    // 16B chunk of row
  if (wv >= n) return;
  const int e0 = __builtin_amdgcn_readfirstlane(rowptr[wv]);
  const int e1 = __builtin_amdgcn_readfirstlane(rowptr[wv + 1]);

  float ra[8] = {}, rb[8] = {};
  int j = e0;
  for (; j + 16 <= e1; j += 16) {
    uint2 pa = edges[j + grp];
    uint2 pb = edges[j + 8 + grp];
    uint4 va = *(const uint4*)&g[(size_t)pa.x * sg + sub * 8];
    uint4 vb = *(const uint4*)&g[(size_t)pb.x * sg + sub * 8];
    float wa = __uint_as_float(pa.y);
    float wb = __uint_as_float(pb.y);
    ra[0] += wa * lo16(va.x); ra[1] += wa * hi16(va.x);
    ra[2] += wa * lo16(va.y); ra[3] += wa * hi16(va.y);
    ra[4] += wa * lo16(va.z); ra[5] += wa * hi16(va.z);
    ra[6] += wa * lo16(va.w); ra[7] += wa * hi16(va.w);
    rb[0] += wb * lo16(vb.x); rb[1] += wb * hi16(vb.x);
    rb[2] += wb * lo16(vb.y); rb[3] += wb * hi16(vb.y);
    rb[4] += wb * lo16(vb.z); rb[5] += wb * hi16(vb.z);
    rb[6] += wb * lo16(vb.w); rb[7] += wb * hi16(vb.w);
  }
  if (j < e1) {                       // exactly one more 8-pack (rows %8)
    uint2 p = edges[j + grp];
    uint4 v = *(const uint4*)&g[(size_t)p.x * sg + sub * 8];
    float w = __uint_as_float(p.y);
    ra[0] += w * lo16(v.x); ra[1] += w * hi16(v.x);
    ra[2] += w * lo16(v.y); ra[3] += w * hi16(v.y);
    ra[4] += w * lo16(v.z); ra[5] += w * hi16(v.z);
    ra[6] += w * lo16(v.w); ra[7] += w * hi16(v.w);
  }
  float r[8];
  #pragma unroll
  for (int e = 0; e < 8; ++e) {
    float t = ra[e] + rb[e];
    t += __shfl_xor(t, 8, 64);
    t += __shfl_xor(t, 16, 64);
    t += __shfl_xor(t, 32, 64);
    r[e] = alpha * t;
  }
  if constexpr (NADD >= 1) {
    uint4 u = *(const uint4*)&a1[(size_t)wv * sa1 + sub * 8];
    r[0] += c1 * lo16(u.x); r[1] += c1 * hi16(u.x);
    r[2] += c1 * lo16(u.y); r[3] += c1 * hi16(u.y);
    r[4] += c1 * lo16(u.z); r[5] += c1 * hi16(u.z);
    r[6] += c1 * lo16(u.w); r[7] += c1 * hi16(u.w);
  }
  if constexpr (NADD >= 2) {
    uint4 u = *(const uint4*)&a2[(size_t)wv * sa2 + sub * 8];
    r[0] += c2 * lo16(u.x); r[1] += c2 * hi16(u.x);
    r[2] += c2 * lo16(u.y); r[3] += c2 * hi16(u.y);
    r[4] += c2 * lo16(u.z); r[5] += c2 * hi16(u.z);
    r[6] += c2 * lo16(u.w); r[7] += c2 * hi16(u.w);
  }
  if constexpr (RELUB) {
    float4 b0 = *(const float4*)&bias[sub * 8];
    float4 b1 = *(const float4*)&bias[sub * 8 + 4];
    r[0] = fmaxf(r[0] + b0.x, 0.f); r[1] = fmaxf(r[1] + b0.y, 0.f);
    r[2] = fmaxf(r[2] + b0.z, 0.f); r[3] = fmaxf(r[3] + b0.w, 0.f);
    r[4] = fmaxf(r[4] + b1.x, 0.f); r[5] = fmaxf(r[5] + b1.y, 0.f);
    r[6] = fmaxf(r[6] + b1.z, 0.f); r[7] = fmaxf(r[7] + b1.w, 0.f);
  }
  if (grp == 0) {
    uint4 o;
    o.x = (uint)f2b(r[0]) | ((uint)f2b(r[1]) << 16);
    o.y = (uint)f2b(r[2]) | ((uint)f2b(r[3]) << 16);
    o.z = (uint)f2b(r[4]) | ((uint)f2b(r[5]) << 16);
    o.w = (uint)f2b(r[6]) | ((uint)f2b(r[7]) << 16);
    *(uint4*)&out[(size_t)wv * so + sub * 8] = o;
  }
}

// ---------------- MFMA GEMM: C[n x Co](bf16) = A[n x Ci](bf16) @ Wt^T --------
// Wt is [Co][Ci] bf16 (B^T row-major). No LDS: B-frags from L1/L2,
// A-frags from global. Block = 4 waves; wave = 4 strips of 16 rows x 64 cols.

template<int Ci, int Co, bool BR>
__global__ __launch_bounds__(256) void gemm_mfma(const ushort* __restrict__ A,
    const ushort* __restrict__ Wt, const float* __restrict__ bias,
    ushort* __restrict__ C, int n)
{
  const int lane = threadIdx.x & 63;
  const int wid  = threadIdx.x >> 6;
  const int rb = blockIdx.x * 256;
  const int cb = blockIdx.y * 64;
  const int lr = lane & 15;            // row/col within fragment
  const int lk = (lane >> 4) << 3;     // k offset: 0,8,16,24
  f32x4 acc[4][4] = {};

  for (int kc = 0; kc < Ci; kc += 64) {
    bf16x8 bfrag[2][4];
    #pragma unroll
    for (int ks = 0; ks < 2; ++ks)
      #pragma unroll
      for (int nt = 0; nt < 4; ++nt)
        bfrag[ks][nt] = *(const bf16x8*)&Wt[(size_t)(cb + nt * 16 + lr) * Ci + kc + ks * 32 + lk];
    #pragma unroll
    for (int s = 0; s < 4; ++s) {
      const int row = rb + (wid * 4 + s) * 16 + lr;
      const ushort* ap = &A[(size_t)row * Ci + kc + lk];
      #pragma unroll
      for (int ks = 0; ks < 2; ++ks) {
        bf16x8 af = {};
        if (row < n) af = *(const bf16x8*)(ap + ks * 32);
        #pragma unroll
        for (int nt = 0; nt < 4; ++nt)
          acc[s][nt] = __builtin_amdgcn_mfma_f32_16x16x32_bf16(af, bfrag[ks][nt], acc[s][nt], 0, 0, 0);
      }
    }
  }

  #pragma unroll
  for (int s = 0; s < 4; ++s) {
    #pragma unroll
    for (int nt = 0; nt < 4; ++nt) {
      const int col = cb + nt * 16 + lr;
      #pragma unroll
      for (int r = 0; r < 4; ++r) {
        const int row = rb + (wid * 4 + s) * 16 + ((lane >> 4) << 2) + r;
        if (row < n) {
          float v = acc[s][nt][r];
          if constexpr (BR) v = fmaxf(v + bias[col], 0.f);
          C[(size_t)row * Co + col] = f2b(v);
        }
      }
    }
  }
}

// ---------------- pooling + head ----------------

__global__ __launch_bounds__(128) void pool_kernel(const ushort* __restrict__ h,
    const int* __restrict__ batch, float* __restrict__ pooled,
    float* __restrict__ gcnt, int n) {
  const int f = threadIdx.x;           // 0..127
  const int i0 = blockIdx.x * 64;
  const int iend = min(i0 + 64, n);
  int cur = batch[i0];
  float acc = 0.f;
  int run = 0;
  for (int i = i0; i < iend; ++i) {
    int b = batch[i];
    float v = b2f(h[(size_t)i * 128 + f]);
    if (b != cur) {
      atomicAdd(&pooled[cur * 128 + f], acc);
      if (f == 0) atomicAdd(&gcnt[cur], (float)run);
      acc = 0.f; run = 0; cur = b;
    }
    acc += v; run++;
  }
  atomicAdd(&pooled[cur * 128 + f], acc);
  if (f == 0) atomicAdd(&gcnt[cur], (float)run);
}

__global__ __launch_bounds__(128) void head_kernel(const float* __restrict__ pooled,
    const float* __restrict__ gcnt, const float* __restrict__ Wl,
    const float* __restrict__ bl, float* __restrict__ outp)
{
  int g = blockIdx.x, t = threadIdx.x;
  float denom = fmaxf(gcnt[g], 1.f);
  float p = pooled[g * 128 + t] / denom;
  __shared__ float s0[128], s1[128];
  s0[t] = p * Wl[t * 2 + 0];
  s1[t] = p * Wl[t * 2 + 1];
  __syncthreads();
  for (int off = 64; off > 0; off >>= 1) {
    if (t < off) { s0[t] += s0[t + off]; s1[t] += s1[t + off]; }
    __syncthreads();
  }
  if (t == 0) {
    float a = s0[0] + bl[0], b = s1[0] + bl[1];
    float m = fmaxf(a, b);
    float z = logf(expf(a - m) + expf(b - m)) + m;
    outp[g * 2 + 0] = a - z;
    outp[g * 2 + 1] = b - z;
  }
}

// ---------------- launch ----------------

extern "C" void kernel_launch(void* const* d_in, const int* in_sizes, int n_in,
                              void* d_out, int out_size, void* d_ws, size_t ws_size,
                              hipStream_t stream) {
  const float* x   = (const float*)d_in[0];
  const int*   ei  = (const int*)d_in[1];
  const float* ea  = (const float*)d_in[2];
  const int* batch = (const int*)d_in[3];
  const float* W1  = (const float*)d_in[4];
  const float* lb1 = (const float*)d_in[5];
  const float* W2  = (const float*)d_in[6];
  const float* lb2 = (const float*)d_in[7];
  const float* W3  = (const float*)d_in[8];
  const float* lb3 = (const float*)d_in[9];
  const float* Wl  = (const float*)d_in[10];
  const float* bl  = (const float*)d_in[11];
  const int* srcv = ei;
  const int* dstv = ei + EE;

  char* w = (char*)d_ws;
  auto alloc = [&](size_t bytes) -> char* {
    char* p = w; w += (bytes + 255) & ~(size_t)255; return p;
  };
  float* deg    = (float*)alloc((size_t)NN * 4);          // becomes dinv
  int*   rowptr = (int*)alloc((size_t)(NN + 1) * 4);
  int*   cnt    = (int*)alloc((size_t)NN * 4);
  int*   bsum   = (int*)alloc(256 * 4);
  int*   rank   = (int*)alloc((size_t)EE * 4);
  uint2* edges  = (uint2*)alloc((size_t)(EE + 8 * NN) * 8); // rows padded to %8
  ushort* xb    = (ushort*)alloc((size_t)NN * 128 * 2);
  ushort* Acat  = (ushort*)alloc((size_t)NN * 320 * 2);   // a_k / Clenshaw / Tx_k
  ushort* Bcat  = (ushort*)alloc((size_t)NN * 320 * 2);   // layer2 blocks; later h3
  ushort* h1    = (ushort*)alloc((size_t)NN * 64 * 2);
  ushort* Wt1   = (ushort*)alloc((size_t)320 * 128 * 2);
  ushort* Wt2   = (ushort*)alloc((size_t)320 * 64 * 2);
  ushort* Wt3   = (ushort*)alloc((size_t)128 * 320 * 2);
  float* pooled = (float*)alloc((size_t)(GG * 128 + GG) * 4);
  float* gcnt   = pooled + GG * 128;
  int*   partial = (int*)Acat;     // scan scratch (Acat unused until GEMM1)
  ushort* h3 = Bcat;               // layer-3 output reuses Bcat

  hipMemsetAsync(deg, 0, (size_t)NN * 4, stream);
  hipMemsetAsync(cnt, 0, (size_t)NN * 4, stream);
  hipMemsetAsync(pooled, 0, (size_t)(GG * 128 + GG) * 4, stream);

  deg_hist_kernel<<<(EE + 255) / 256, 256, 0, stream>>>(srcv, dstv, ea, deg, cnt, rank, EE);
  dinv_kernel<<<(NN + 255) / 256, 256, 0, stream>>>(deg, NN);
  const int nb = (NN + 255) / 256;  // 196
  scan1<<<nb, 256, 0, stream>>>(cnt, partial, bsum, NN);
  scan2<<<1, 256, 0, stream>>>(bsum, nb);
  scan3<<<nb, 256, 0, stream>>>(partial, bsum, rowptr, NN);
  scatter_kernel<<<(EE + 255) / 256, 256, 0, stream>>>(srcv, dstv, ea, deg, rowptr, rank,
                                                       edges, EE);
  pad_kernel<<<nb, 256, 0, stream>>>(rowptr, cnt, edges, NN);

  cvt_x<<<(NN * 128 / 4 + 255) / 256, 256, 0, stream>>>(x, xb, NN * 128 / 4);
  cvt_w<<<(320 * 128 + 320 * 64 + 128 * 320 + 255) / 256, 256, 0, stream>>>(
      W1, W2, W3, Wt1, Wt2, Wt3);

  const int PG = (NN + 3) / 4;       // prop blocks (4 waves each)
  const int GX = (NN + 255) / 256;   // gemm row-blocks

  ushort* A0 = Acat + 0 * 64;  ushort* A1 = Acat + 1 * 64;  ushort* A2 = Acat + 2 * 64;
  ushort* A3 = Acat + 3 * 64;  ushort* A4 = Acat + 4 * 64;
  ushort* B0 = Bcat + 0 * 64;  ushort* B1 = Bcat + 1 * 64;  ushort* B2 = Bcat + 2 * 64;
  ushort* B3 = Bcat + 3 * 64;  ushort* B4 = Bcat + 4 * 64;
  const int S = 320;

  // ---- Layer 1 (Clenshaw): a_k = x @ W1_k  -> Acat[50000][320] ----
  gemm_mfma<128, 320, false><<<dim3(GX, 5), 256, 0, stream>>>(xb, Wt1, nullptr, Acat, NN);
  prop_kernel<1, false><<<PG, 256, 0, stream>>>(rowptr, edges, A4, S, A3, S, 1.f,
      nullptr, 0, 0.f, nullptr, A3, S, NN, 2.f);
  prop_kernel<2, false><<<PG, 256, 0, stream>>>(rowptr, edges, A3, S, A2, S, 1.f,
      A4, S, -1.f, nullptr, A2, S, NN, 2.f);
  prop_kernel<2, false><<<PG, 256, 0, stream>>>(rowptr, edges, A2, S, A1, S, 1.f,
      A3, S, -1.f, nullptr, A1, S, NN, 2.f);
  prop_kernel<2, true><<<PG, 256, 0, stream>>>(rowptr, edges, A1, S, A0, S, 1.f,
      A2, S, -1.f, lb1, h1, 64, NN, 1.f);

  // ---- Layer 2 (Clenshaw): a_k = h1 @ W2_k -> Bcat ----
  gemm_mfma<64, 320, false><<<dim3(GX, 5), 256, 0, stream>>>(h1, Wt2, nullptr, Bcat, NN);
  prop_kernel<1, false><<<PG, 256, 0, stream>>>(rowptr, edges, B4, S, B3, S, 1.f,
      nullptr, 0, 0.f, nullptr, B3, S, NN, 2.f);
  prop_kernel<2, false><<<PG, 256, 0, stream>>>(rowptr, edges, B3, S, B2, S, 1.f,
      B4, S, -1.f, nullptr, B2, S, NN, 2.f);
  prop_kernel<2, false><<<PG, 256, 0, stream>>>(rowptr, edges, B2, S, B1, S, 1.f,
      B3, S, -1.f, nullptr, B1, S, NN, 2.f);
  // h2 -> Acat block 0 (Tx0), strided
  prop_kernel<2, true><<<PG, 256, 0, stream>>>(rowptr, edges, B1, S, B0, S, 1.f,
      B2, S, -1.f, lb2, A0, S, NN, 1.f);

  // ---- Layer 3 (forward recursion, Tx_k in Acat blocks) ----
  prop_kernel<0, false><<<PG, 256, 0, stream>>>(rowptr, edges, A0, S, nullptr, 0, 0.f,
      nullptr, 0, 0.f, nullptr, A1, S, NN, 1.f);
  prop_kernel<1, false><<<PG, 256, 0, stream>>>(rowptr, edges, A1, S, A0, S, -1.f,
      nullptr, 0, 0.f, nullptr, A2, S, NN, 2.f);
  prop_kernel<1, false><<<PG, 256, 0, stream>>>(rowptr, edges, A2, S, A1, S, -1.f,
      nullptr, 0, 0.f, nullptr, A3, S, NN, 2.f);
  prop_kernel<1, false><<<PG, 256, 0, stream>>>(rowptr, edges, A3, S, A2, S, -1.f,
      nullptr, 0, 0.f, nullptr, A4, S, NN, 2.f);
  // h3 = relu([Tx0|..|Tx4] @ W3stack + b3)
  gemm_mfma<320, 128, true><<<dim3(GX, 2), 256, 0, stream>>>(Acat, Wt3, lb3, h3, NN);

  // ---- pool + head ----
  pool_kernel<<<(NN + 63) / 64, 128, 0, stream>>>(h3, batch, pooled, gcnt, NN);
  head_kernel<<<GG, 128, 0, stream>>>(pooled, gcnt, Wl, bl, (float*)d_out);
}

// Round 8
// 639.769 us; speedup vs baseline: 1.4408x; 1.0432x over previous
//
#include <hip/hip_runtime.h>
#include <hip/hip_bf16.h>

#define NN 50000
#define EE 1600000
#define GG 500

#define HB 6250          // hist blocks in mega1 (6250*256 == EE)
#define GX1 196          // gemm1 row-blocks = ceil(NN/256)
#define GB1 (GX1 * 5)    // gemm1 blocks (5 column tiles of 64)
#define CVB 240          // cvt_w blocks (61440 elems / 256)

typedef __bf16 bf16x8 __attribute__((ext_vector_type(8)));
typedef float  f32x4  __attribute__((ext_vector_type(4)));

__device__ __forceinline__ float b2f(ushort u) {
  return __uint_as_float(((unsigned)u) << 16);
}
__device__ __forceinline__ ushort f2b(float f) {
  unsigned u = __float_as_uint(f);
  unsigned r = (u + 0x7fff + ((u >> 16) & 1)) >> 16;   // RNE
  return (ushort)r;
}
__device__ __forceinline__ float lo16(uint v) { return __uint_as_float(v << 16); }
__device__ __forceinline__ float hi16(uint v) { return __uint_as_float(v & 0xffff0000u); }

// ---------------- mega phase 1: hist ∪ gemm1(fp32 inputs) ∪ cvt_w ----------------
// All three sub-tasks are mutually independent; hist is atomic-rate bound with
// BW/VALU/MFMA idle, so gemm1+cvt ride along for free.

__global__ __launch_bounds__(256) void mega1(
    const int* __restrict__ src, const int* __restrict__ dst,
    const float* __restrict__ ea, float* __restrict__ deg,
    int* __restrict__ cnt, int* __restrict__ rank,
    const float* __restrict__ x, const float* __restrict__ W1,
    ushort* __restrict__ Acat,
    const float* __restrict__ W2, const float* __restrict__ W3,
    ushort* __restrict__ Wt2, ushort* __restrict__ Wt3)
{
  int b = blockIdx.x;
  if (b < HB) {
    // ---- histogram: deg[src] += ea (fire-and-forget); rank = cnt[dst]++ ----
    int i = b * 256 + threadIdx.x;
    if (i < EE) {
      atomicAdd(&deg[src[i]], ea[i]);
      rank[i] = atomicAdd(&cnt[dst[i]], 1);
    }
    return;
  }
  b -= HB;
  if (b < GB1) {
    // ---- gemm1: Acat[n][320] = bf16(x[n][128]) @ bf16(W1_k)  (fp32 sources) ----
    const int bx = b % GX1, by = b / GX1;
    const int lane = threadIdx.x & 63;
    const int wid  = threadIdx.x >> 6;
    const int rb = bx * 256;
    const int cb = by * 64;
    const int lr = lane & 15;
    const int lk = (lane >> 4) << 3;
    f32x4 acc[4][4] = {};
    for (int kc = 0; kc < 128; kc += 64) {
      bf16x8 bfrag[2][4];
      #pragma unroll
      for (int ks = 0; ks < 2; ++ks)
        #pragma unroll
        for (int nt = 0; nt < 4; ++nt) {
          int col = cb + nt * 16 + lr;        // 0..319
          int kk  = kc + ks * 32 + lk;
          const float* wp = &W1[((size_t)(col >> 6) * 128 + kk) * 64 + (col & 63)];
          union { bf16x8 v; ushort u[8]; } bu;
          #pragma unroll
          for (int t = 0; t < 8; ++t) bu.u[t] = f2b(wp[t * 64]);
          bfrag[ks][nt] = bu.v;
        }
      #pragma unroll
      for (int s = 0; s < 4; ++s) {
        const int row = rb + (wid * 4 + s) * 16 + lr;
        #pragma unroll
        for (int ks = 0; ks < 2; ++ks) {
          union { bf16x8 v; ushort u[8]; } au;
          if (row < NN) {
            const float* ap = &x[(size_t)row * 128 + kc + ks * 32 + lk];
            float4 f0 = *(const float4*)ap;
            float4 f1 = *(const float4*)(ap + 4);
            au.u[0] = f2b(f0.x); au.u[1] = f2b(f0.y);
            au.u[2] = f2b(f0.z); au.u[3] = f2b(f0.w);
            au.u[4] = f2b(f1.x); au.u[5] = f2b(f1.y);
            au.u[6] = f2b(f1.z); au.u[7] = f2b(f1.w);
          } else {
            au.v = bf16x8{};
          }
          #pragma unroll
          for (int nt = 0; nt < 4; ++nt)
            acc[s][nt] = __builtin_amdgcn_mfma_f32_16x16x32_bf16(au.v, bfrag[ks][nt],
                                                                 acc[s][nt], 0, 0, 0);
        }
      }
    }
    #pragma unroll
    for (int s = 0; s < 4; ++s)
      #pragma unroll
      for (int nt = 0; nt < 4; ++nt) {
        const int col = cb + nt * 16 + lr;
        #pragma unroll
        for (int r = 0; r < 4; ++r) {
          const int row = rb + (wid * 4 + s) * 16 + ((lane >> 4) << 2) + r;
          if (row < NN) Acat[(size_t)row * 320 + col] = f2b(acc[s][nt][r]);
        }
      }
    return;
  }
  b -= GB1;
  // ---- cvt_w: Wt2[320][64], Wt3[128][320] from fp32 ----
  int t = b * 256 + threadIdx.x;      // 0..61439
  if (t < 320 * 64) {
    int j = t / 64, k = t % 64;
    Wt2[t] = f2b(W2[((size_t)(j >> 6) * 64 + k) * 64 + (j & 63)]);
  } else {
    int t2 = t - 320 * 64;            // < 128*320
    int j = t2 / 320, k = t2 % 320;
    Wt3[t2] = f2b(W3[(size_t)k * 128 + j]);
  }
}

// ---------------- scans (8-padded counts) + fused dinv / pad ----------------

__global__ void scan1(const int* __restrict__ cnt, float* __restrict__ deg,
                      int* __restrict__ partial, int* __restrict__ bsum, int n) {
  __shared__ int s[256];
  int t = threadIdx.x, i = blockIdx.x * 256 + t;
  if (i < n) { float d = deg[i]; deg[i] = (d > 0.f) ? (1.0f / sqrtf(d)) : 0.f; }
  int v = (i < n) ? ((cnt[i] + 7) & ~7) : 0;
  s[t] = v; __syncthreads();
  for (int off = 1; off < 256; off <<= 1) {
    int xv = (t >= off) ? s[t - off] : 0;
    __syncthreads(); s[t] += xv; __syncthreads();
  }
  if (i < n) partial[i] = s[t];
  if (t == 255) bsum[blockIdx.x] = s[255];
}

__global__ void scan2(int* __restrict__ bsum, int nb) {
  __shared__ int s[256];
  int t = threadIdx.x;
  int v = (t < nb) ? bsum[t] : 0;
  s[t] = v; __syncthreads();
  for (int off = 1; off < 256; off <<= 1) {
    int xv = (t >= off) ? s[t - off] : 0;
    __syncthreads(); s[t] += xv; __syncthreads();
  }
  if (t < nb) bsum[t] = s[t];
}

__global__ void scan3(const int* __restrict__ partial, const int* __restrict__ bsum,
                      const int* __restrict__ cnt, int* __restrict__ rowptr,
                      uint2* __restrict__ edges, int n) {
  int i = blockIdx.x * 256 + threadIdx.x;
  if (i < n) {
    int off = (blockIdx.x > 0) ? bsum[blockIdx.x - 1] : 0;
    int end = partial[i] + off;           // padded end of row i
    rowptr[i + 1] = end;
    if (i == 0) rowptr[0] = 0;
    int c = cnt[i];
    int start = end - ((c + 7) & ~7);
    for (int q = start + c; q < end; ++q) edges[q] = make_uint2(0u, 0u);  // fillers
  }
}

// atomic-free scatter: pos = rowptr[d] + rank
__global__ void scatter_kernel(const int* __restrict__ src, const int* __restrict__ dst,
                               const float* __restrict__ ea, const float* __restrict__ dinv,
                               const int* __restrict__ rowptr, const int* __restrict__ rank,
                               uint2* __restrict__ edges, int e) {
  int i = blockIdx.x * blockDim.x + threadIdx.x;
  if (i < e) {
    int s = src[i], d = dst[i];
    float w = -dinv[s] * ea[i] * dinv[d];
    edges[rowptr[d] + rank[i]] = make_uint2((unsigned)s, __float_as_uint(w));
  }
}

// ---------------- sparse propagation V4 (8 edges per gather) ----------------

template<int NADD, bool RELUB>
__global__ __launch_bounds__(256) void prop_kernel(
    const int* __restrict__ rowptr, const uint2* __restrict__ edges,
    const ushort* __restrict__ g, int sg,
    const ushort* __restrict__ a1, int sa1, float c1,
    const ushort* __restrict__ a2, int sa2, float c2,
    const float* __restrict__ bias,
    ushort* __restrict__ out, int so, int n, float alpha)
{
  int wv = blockIdx.x * 4 + (threadIdx.x >> 6);
  wv = __builtin_amdgcn_readfirstlane(wv);
  const int lane = threadIdx.x & 63;
  const int grp = lane >> 3;   // edge within 8-pack
  const int sub = lane & 7;    // 16B chunk of row
  if (wv >= n) return;
  const int e0 = __builtin_amdgcn_readfirstlane(rowptr[wv]);
  const int e1 = __builtin_amdgcn_readfirstlane(rowptr[wv + 1]);

  float ra[8] = {}, rb[8] = {};
  int j = e0;
  for (; j + 16 <= e1; j += 16) {
    uint2 pa = edges[j + grp];
    uint2 pb = edges[j + 8 + grp];
    uint4 va = *(const uint4*)&g[(size_t)pa.x * sg + sub * 8];
    uint4 vb = *(const uint4*)&g[(size_t)pb.x * sg + sub * 8];
    float wa = __uint_as_float(pa.y);
    float wb = __uint_as_float(pb.y);
    ra[0] += wa * lo16(va.x); ra[1] += wa * hi16(va.x);
    ra[2] += wa * lo16(va.y); ra[3] += wa * hi16(va.y);
    ra[4] += wa * lo16(va.z); ra[5] += wa * hi16(va.z);
    ra[6] += wa * lo16(va.w); ra[7] += wa * hi16(va.w);
    rb[0] += wb * lo16(vb.x); rb[1] += wb * hi16(vb.x);
    rb[2] += wb * lo16(vb.y); rb[3] += wb * hi16(vb.y);
    rb[4] += wb * lo16(vb.z); rb[5] += wb * hi16(vb.z);
    rb[6] += wb * lo16(vb.w); rb[7] += wb * hi16(vb.w);
  }
  if (j < e1) {                       // exactly one more 8-pack (rows %8)
    uint2 p = edges[j + grp];
    uint4 v = *(const uint4*)&g[(size_t)p.x * sg + sub * 8];
    float w = __uint_as_float(p.y);
    ra[0] += w * lo16(v.x); ra[1] += w * hi16(v.x);
    ra[2] += w * lo16(v.y); ra[3] += w * hi16(v.y);
    ra[4] += w * lo16(v.z); ra[5] += w * hi16(v.z);
    ra[6] += w * lo16(v.w); ra[7] += w * hi16(v.w);
  }
  float r[8];
  #pragma unroll
  for (int e = 0; e < 8; ++e) {
    float t = ra[e] + rb[e];
    t += __shfl_xor(t, 8, 64);
    t += __shfl_xor(t, 16, 64);
    t += __shfl_xor(t, 32, 64);
    r[e] = alpha * t;
  }
  if constexpr (NADD >= 1) {
    uint4 u = *(const uint4*)&a1[(size_t)wv * sa1 + sub * 8];
    r[0] += c1 * lo16(u.x); r[1] += c1 * hi16(u.x);
    r[2] += c1 * lo16(u.y); r[3] += c1 * hi16(u.y);
    r[4] += c1 * lo16(u.z); r[5] += c1 * hi16(u.z);
    r[6] += c1 * lo16(u.w); r[7] += c1 * hi16(u.w);
  }
  if constexpr (NADD >= 2) {
    uint4 u = *(const uint4*)&a2[(size_t)wv * sa2 + sub * 8];
    r[0] += c2 * lo16(u.x); r[1] += c2 * hi16(u.x);
    r[2] += c2 * lo16(u.y); r[3] += c2 * hi16(u.y);
    r[4] += c2 * lo16(u.z); r[5] += c2 * hi16(u.z);
    r[6] += c2 * lo16(u.w); r[7] += c2 * hi16(u.w);
  }
  if constexpr (RELUB) {
    float4 b0 = *(const float4*)&bias[sub * 8];
    float4 b1 = *(const float4*)&bias[sub * 8 + 4];
    r[0] = fmaxf(r[0] + b0.x, 0.f); r[1] = fmaxf(r[1] + b0.y, 0.f);
    r[2] = fmaxf(r[2] + b0.z, 0.f); r[3] = fmaxf(r[3] + b0.w, 0.f);
    r[4] = fmaxf(r[4] + b1.x, 0.f); r[5] = fmaxf(r[5] + b1.y, 0.f);
    r[6] = fmaxf(r[6] + b1.z, 0.f); r[7] = fmaxf(r[7] + b1.w, 0.f);
  }
  if (grp == 0) {
    uint4 o;
    o.x = (uint)f2b(r[0]) | ((uint)f2b(r[1]) << 16);
    o.y = (uint)f2b(r[2]) | ((uint)f2b(r[3]) << 16);
    o.z = (uint)f2b(r[4]) | ((uint)f2b(r[5]) << 16);
    o.w = (uint)f2b(r[6]) | ((uint)f2b(r[7]) << 16);
    *(uint4*)&out[(size_t)wv * so + sub * 8] = o;
  }
}

// ---------------- MFMA GEMM (bf16 in, bf16 out) ----------------

template<int Ci, int Co, bool BR>
__global__ __launch_bounds__(256) void gemm_mfma(const ushort* __restrict__ A,
    const ushort* __restrict__ Wt, const float* __restrict__ bias,
    ushort* __restrict__ C, int n)
{
  const int lane = threadIdx.x & 63;
  const int wid  = threadIdx.x >> 6;
  const int rb = blockIdx.x * 256;
  const int cb = blockIdx.y * 64;
  const int lr = lane & 15;
  const int lk = (lane >> 4) << 3;
  f32x4 acc[4][4] = {};

  for (int kc = 0; kc < Ci; kc += 64) {
    bf16x8 bfrag[2][4];
    #pragma unroll
    for (int ks = 0; ks < 2; ++ks)
      #pragma unroll
      for (int nt = 0; nt < 4; ++nt)
        bfrag[ks][nt] = *(const bf16x8*)&Wt[(size_t)(cb + nt * 16 + lr) * Ci + kc + ks * 32 + lk];
    #pragma unroll
    for (int s = 0; s < 4; ++s) {
      const int row = rb + (wid * 4 + s) * 16 + lr;
      const ushort* ap = &A[(size_t)row * Ci + kc + lk];
      #pragma unroll
      for (int ks = 0; ks < 2; ++ks) {
        bf16x8 af = {};
        if (row < n) af = *(const bf16x8*)(ap + ks * 32);
        #pragma unroll
        for (int nt = 0; nt < 4; ++nt)
          acc[s][nt] = __builtin_amdgcn_mfma_f32_16x16x32_bf16(af, bfrag[ks][nt], acc[s][nt], 0, 0, 0);
      }
    }
  }

  #pragma unroll
  for (int s = 0; s < 4; ++s)
    #pragma unroll
    for (int nt = 0; nt < 4; ++nt) {
      const int col = cb + nt * 16 + lr;
      #pragma unroll
      for (int r = 0; r < 4; ++r) {
        const int row = rb + (wid * 4 + s) * 16 + ((lane >> 4) << 2) + r;
        if (row < n) {
          float v = acc[s][nt][r];
          if constexpr (BR) v = fmaxf(v + bias[col], 0.f);
          C[(size_t)row * Co + col] = f2b(v);
        }
      }
    }
}

// ---------------- pooling + head ----------------

__global__ __launch_bounds__(128) void pool_kernel(const ushort* __restrict__ h,
    const int* __restrict__ batch, float* __restrict__ pooled,
    float* __restrict__ gcnt, int n) {
  const int f = threadIdx.x;
  const int i0 = blockIdx.x * 64;
  const int iend = min(i0 + 64, n);
  int cur = batch[i0];
  float acc = 0.f;
  int run = 0;
  for (int i = i0; i < iend; ++i) {
    int b = batch[i];
    float v = b2f(h[(size_t)i * 128 + f]);
    if (b != cur) {
      atomicAdd(&pooled[cur * 128 + f], acc);
      if (f == 0) atomicAdd(&gcnt[cur], (float)run);
      acc = 0.f; run = 0; cur = b;
    }
    acc += v; run++;
  }
  atomicAdd(&pooled[cur * 128 + f], acc);
  if (f == 0) atomicAdd(&gcnt[cur], (float)run);
}

__global__ __launch_bounds__(128) void head_kernel(const float* __restrict__ pooled,
    const float* __restrict__ gcnt, const float* __restrict__ Wl,
    const float* __restrict__ bl, float* __restrict__ outp)
{
  int g = blockIdx.x, t = threadIdx.x;
  float denom = fmaxf(gcnt[g], 1.f);
  float p = pooled[g * 128 + t] / denom;
  __shared__ float s0[128], s1[128];
  s0[t] = p * Wl[t * 2 + 0];
  s1[t] = p * Wl[t * 2 + 1];
  __syncthreads();
  for (int off = 64; off > 0; off >>= 1) {
    if (t < off) { s0[t] += s0[t + off]; s1[t] += s1[t + off]; }
    __syncthreads();
  }
  if (t == 0) {
    float a = s0[0] + bl[0], b = s1[0] + bl[1];
    float m = fmaxf(a, b);
    float z = logf(expf(a - m) + expf(b - m)) + m;
    outp[g * 2 + 0] = a - z;
    outp[g * 2 + 1] = b - z;
  }
}

// ---------------- launch ----------------

extern "C" void kernel_launch(void* const* d_in, const int* in_sizes, int n_in,
                              void* d_out, int out_size, void* d_ws, size_t ws_size,
                              hipStream_t stream) {
  const float* x   = (const float*)d_in[0];
  const int*   ei  = (const int*)d_in[1];
  const float* ea  = (const float*)d_in[2];
  const int* batch = (const int*)d_in[3];
  const float* W1  = (const float*)d_in[4];
  const float* lb1 = (const float*)d_in[5];
  const float* W2  = (const float*)d_in[6];
  const float* lb2 = (const float*)d_in[7];
  const float* W3  = (const float*)d_in[8];
  const float* lb3 = (const float*)d_in[9];
  const float* Wl  = (const float*)d_in[10];
  const float* bl  = (const float*)d_in[11];
  const int* srcv = ei;
  const int* dstv = ei + EE;

  char* w = (char*)d_ws;
  auto alloc = [&](size_t bytes) -> char* {
    char* p = w; w += (bytes + 255) & ~(size_t)255; return p;
  };
  // zero-init region: deg, cnt, pooled+gcnt contiguous (one memset)
  float* deg    = (float*)alloc((size_t)NN * 4);          // becomes dinv in scan1
  int*   cnt    = (int*)alloc((size_t)NN * 4);
  float* pooled = (float*)alloc((size_t)(GG * 128 + GG) * 4);
  float* gcnt   = pooled + GG * 128;
  char*  zero_end = w;
  int*   rowptr = (int*)alloc((size_t)(NN + 1) * 4);
  int*   bsum   = (int*)alloc(256 * 4);
  int*   rank   = (int*)alloc((size_t)EE * 4);
  uint2* edges  = (uint2*)alloc((size_t)(EE + 8 * NN) * 8); // rows padded to %8
  ushort* Acat  = (ushort*)alloc((size_t)NN * 320 * 2);   // a_k / Clenshaw / Tx_k
  ushort* Bcat  = (ushort*)alloc((size_t)NN * 320 * 2);   // layer2 blocks; later h3
  ushort* h1    = (ushort*)alloc((size_t)NN * 64 * 2);
  ushort* Wt2   = (ushort*)alloc((size_t)320 * 64 * 2);
  ushort* Wt3   = (ushort*)alloc((size_t)128 * 320 * 2);
  int*   partial = (int*)Bcat;     // scan scratch (Bcat unused until gemm2)
  ushort* h3 = Bcat;               // layer-3 output reuses Bcat

  hipMemsetAsync(deg, 0, (size_t)(zero_end - (char*)deg), stream);

  // phase 1: histogram ∪ gemm1 ∪ cvt_w in one launch
  mega1<<<HB + GB1 + CVB, 256, 0, stream>>>(srcv, dstv, ea, deg, cnt, rank,
                                            x, W1, Acat, W2, W3, Wt2, Wt3);

  const int nb = (NN + 255) / 256;  // 196
  scan1<<<nb, 256, 0, stream>>>(cnt, deg, partial, bsum, NN);      // + dinv
  scan2<<<1, 256, 0, stream>>>(bsum, nb);
  scan3<<<nb, 256, 0, stream>>>(partial, bsum, cnt, rowptr, edges, NN);  // + pad
  scatter_kernel<<<(EE + 255) / 256, 256, 0, stream>>>(srcv, dstv, ea, deg, rowptr, rank,
                                                       edges, EE);

  const int PG = (NN + 3) / 4;       // prop blocks (4 waves each)
  const int GX = (NN + 255) / 256;   // gemm row-blocks

  ushort* A0 = Acat + 0 * 64;  ushort* A1 = Acat + 1 * 64;  ushort* A2 = Acat + 2 * 64;
  ushort* A3 = Acat + 3 * 64;  ushort* A4 = Acat + 4 * 64;
  ushort* B0 = Bcat + 0 * 64;  ushort* B1 = Bcat + 1 * 64;  ushort* B2 = Bcat + 2 * 64;
  ushort* B3 = Bcat + 3 * 64;  ushort* B4 = Bcat + 4 * 64;
  const int S = 320;

  // ---- Layer 1 (Clenshaw), a_k already in Acat from mega1 ----
  prop_kernel<1, false><<<PG, 256, 0, stream>>>(rowptr, edges, A4, S, A3, S, 1.f,
      nullptr, 0, 0.f, nullptr, A3, S, NN, 2.f);
  prop_kernel<2, false><<<PG, 256, 0, stream>>>(rowptr, edges, A3, S, A2, S, 1.f,
      A4, S, -1.f, nullptr, A2, S, NN, 2.f);
  prop_kernel<2, false><<<PG, 256, 0, stream>>>(rowptr, edges, A2, S, A1, S, 1.f,
      A3, S, -1.f, nullptr, A1, S, NN, 2.f);
  prop_kernel<2, true><<<PG, 256, 0, stream>>>(rowptr, edges, A1, S, A0, S, 1.f,
      A2, S, -1.f, lb1, h1, 64, NN, 1.f);

  // ---- Layer 2 (Clenshaw): a_k = h1 @ W2_k -> Bcat ----
  gemm_mfma<64, 320, false><<<dim3(GX, 5), 256, 0, stream>>>(h1, Wt2, nullptr, Bcat, NN);
  prop_kernel<1, false><<<PG, 256, 0, stream>>>(rowptr, edges, B4, S, B3, S, 1.f,
      nullptr, 0, 0.f, nullptr, B3, S, NN, 2.f);
  prop_kernel<2, false><<<PG, 256, 0, stream>>>(rowptr, edges, B3, S, B2, S, 1.f,
      B4, S, -1.f, nullptr, B2, S, NN, 2.f);
  prop_kernel<2, false><<<PG, 256, 0, stream>>>(rowptr, edges, B2, S, B1, S, 1.f,
      B3, S, -1.f, nullptr, B1, S, NN, 2.f);
  // h2 -> Acat block 0 (Tx0), strided
  prop_kernel<2, true><<<PG, 256, 0, stream>>>(rowptr, edges, B1, S, B0, S, 1.f,
      B2, S, -1.f, lb2, A0, S, NN, 1.f);

  // ---- Layer 3 (forward recursion, Tx_k in Acat blocks) ----
  prop_kernel<0, false><<<PG, 256, 0, stream>>>(rowptr, edges, A0, S, nullptr, 0, 0.f,
      nullptr, 0, 0.f, nullptr, A1, S, NN, 1.f);
  prop_kernel<1, false><<<PG, 256, 0, stream>>>(rowptr, edges, A1, S, A0, S, -1.f,
      nullptr, 0, 0.f, nullptr, A2, S, NN, 2.f);
  prop_kernel<1, false><<<PG, 256, 0, stream>>>(rowptr, edges, A2, S, A1, S, -1.f,
      nullptr, 0, 0.f, nullptr, A3, S, NN, 2.f);
  prop_kernel<1, false><<<PG, 256, 0, stream>>>(rowptr, edges, A3, S, A2, S, -1.f,
      nullptr, 0, 0.f, nullptr, A4, S, NN, 2.f);
  // h3 = relu([Tx0|..|Tx4] @ W3stack + b3)
  gemm_mfma<320, 128, true><<<dim3(GX, 2), 256, 0, stream>>>(Acat, Wt3, lb3, h3, NN);

  // ---- pool + head ----
  pool_kernel<<<(NN + 63) / 64, 128, 0, stream>>>(h3, batch, pooled, gcnt, NN);
  head_kernel<<<GG, 128, 0, stream>>>(pooled, gcnt, Wl, bl, (float*)d_out);
}

// Round 9
// 614.852 us; speedup vs baseline: 1.4992x; 1.0405x over previous
//
#include <hip/hip_runtime.h>
#include <hip/hip_bf16.h>

#define NN 50000
#define EE 1600000
#define GG 500

#define HB 6250          // hist blocks in mega1 (6250*256 == EE)
#define GX1 196          // gemm1 row-blocks = ceil(NN/256)
#define GB1 (GX1 * 5)    // gemm1 blocks (5 column tiles of 64)
#define CVB 240          // cvt_w blocks (61440 elems / 256)

typedef __bf16 bf16x8 __attribute__((ext_vector_type(8)));
typedef float  f32x4  __attribute__((ext_vector_type(4)));

__device__ __forceinline__ float b2f(ushort u) {
  return __uint_as_float(((unsigned)u) << 16);
}
__device__ __forceinline__ ushort f2b(float f) {
  unsigned u = __float_as_uint(f);
  unsigned r = (u + 0x7fff + ((u >> 16) & 1)) >> 16;   // RNE
  return (ushort)r;
}
__device__ __forceinline__ float lo16(uint v) { return __uint_as_float(v << 16); }
__device__ __forceinline__ float hi16(uint v) { return __uint_as_float(v & 0xffff0000u); }

// ---------------- mega phase 1: hist ∪ gemm1(fp32 inputs) ∪ cvt_w ----------------

__global__ __launch_bounds__(256) void mega1(
    const int* __restrict__ src, const int* __restrict__ dst,
    const float* __restrict__ ea, float* __restrict__ deg,
    int* __restrict__ cnt, int* __restrict__ rank,
    const float* __restrict__ x, const float* __restrict__ W1,
    ushort* __restrict__ Acat,
    const float* __restrict__ W2, const float* __restrict__ W3,
    ushort* __restrict__ Wt2, ushort* __restrict__ Wt3)
{
  int b = blockIdx.x;
  if (b < HB) {
    int i = b * 256 + threadIdx.x;
    if (i < EE) {
      atomicAdd(&deg[src[i]], ea[i]);
      rank[i] = atomicAdd(&cnt[dst[i]], 1);
    }
    return;
  }
  b -= HB;
  if (b < GB1) {
    const int bx = b % GX1, by = b / GX1;
    const int lane = threadIdx.x & 63;
    const int wid  = threadIdx.x >> 6;
    const int rb = bx * 256;
    const int cb = by * 64;
    const int lr = lane & 15;
    const int lk = (lane >> 4) << 3;
    f32x4 acc[4][4] = {};
    for (int kc = 0; kc < 128; kc += 64) {
      bf16x8 bfrag[2][4];
      #pragma unroll
      for (int ks = 0; ks < 2; ++ks)
        #pragma unroll
        for (int nt = 0; nt < 4; ++nt) {
          int col = cb + nt * 16 + lr;        // 0..319
          int kk  = kc + ks * 32 + lk;
          const float* wp = &W1[((size_t)(col >> 6) * 128 + kk) * 64 + (col & 63)];
          union { bf16x8 v; ushort u[8]; } bu;
          #pragma unroll
          for (int t = 0; t < 8; ++t) bu.u[t] = f2b(wp[t * 64]);
          bfrag[ks][nt] = bu.v;
        }
      #pragma unroll
      for (int s = 0; s < 4; ++s) {
        const int row = rb + (wid * 4 + s) * 16 + lr;
        #pragma unroll
        for (int ks = 0; ks < 2; ++ks) {
          union { bf16x8 v; ushort u[8]; } au;
          if (row < NN) {
            const float* ap = &x[(size_t)row * 128 + kc + ks * 32 + lk];
            float4 f0 = *(const float4*)ap;
            float4 f1 = *(const float4*)(ap + 4);
            au.u[0] = f2b(f0.x); au.u[1] = f2b(f0.y);
            au.u[2] = f2b(f0.z); au.u[3] = f2b(f0.w);
            au.u[4] = f2b(f1.x); au.u[5] = f2b(f1.y);
            au.u[6] = f2b(f1.z); au.u[7] = f2b(f1.w);
          } else {
            au.v = bf16x8{};
          }
          #pragma unroll
          for (int nt = 0; nt < 4; ++nt)
            acc[s][nt] = __builtin_amdgcn_mfma_f32_16x16x32_bf16(au.v, bfrag[ks][nt],
                                                                 acc[s][nt], 0, 0, 0);
        }
      }
    }
    #pragma unroll
    for (int s = 0; s < 4; ++s)
      #pragma unroll
      for (int nt = 0; nt < 4; ++nt) {
        const int col = cb + nt * 16 + lr;
        #pragma unroll
        for (int r = 0; r < 4; ++r) {
          const int row = rb + (wid * 4 + s) * 16 + ((lane >> 4) << 2) + r;
          if (row < NN) Acat[(size_t)row * 320 + col] = f2b(acc[s][nt][r]);
        }
      }
    return;
  }
  b -= GB1;
  int t = b * 256 + threadIdx.x;      // 0..61439
  if (t < 320 * 64) {
    int j = t / 64, k = t % 64;
    Wt2[t] = f2b(W2[((size_t)(j >> 6) * 64 + k) * 64 + (j & 63)]);
  } else {
    int t2 = t - 320 * 64;            // < 128*320
    int j = t2 / 320, k = t2 % 320;
    Wt3[t2] = f2b(W3[(size_t)k * 128 + j]);
  }
}

// ---------------- scans (4-padded counts) + fused dinv / pad ----------------

__global__ void scan1(const int* __restrict__ cnt, float* __restrict__ deg,
                      int* __restrict__ partial, int* __restrict__ bsum, int n) {
  __shared__ int s[256];
  int t = threadIdx.x, i = blockIdx.x * 256 + t;
  if (i < n) { float d = deg[i]; deg[i] = (d > 0.f) ? (1.0f / sqrtf(d)) : 0.f; }
  int v = (i < n) ? ((cnt[i] + 3) & ~3) : 0;
  s[t] = v; __syncthreads();
  for (int off = 1; off < 256; off <<= 1) {
    int xv = (t >= off) ? s[t - off] : 0;
    __syncthreads(); s[t] += xv; __syncthreads();
  }
  if (i < n) partial[i] = s[t];
  if (t == 255) bsum[blockIdx.x] = s[255];
}

__global__ void scan2(int* __restrict__ bsum, int nb) {
  __shared__ int s[256];
  int t = threadIdx.x;
  int v = (t < nb) ? bsum[t] : 0;
  s[t] = v; __syncthreads();
  for (int off = 1; off < 256; off <<= 1) {
    int xv = (t >= off) ? s[t - off] : 0;
    __syncthreads(); s[t] += xv; __syncthreads();
  }
  if (t < nb) bsum[t] = s[t];
}

__global__ void scan3(const int* __restrict__ partial, const int* __restrict__ bsum,
                      const int* __restrict__ cnt, int* __restrict__ rowptr,
                      uint2* __restrict__ edges, int n) {
  int i = blockIdx.x * 256 + threadIdx.x;
  if (i < n) {
    int off = (blockIdx.x > 0) ? bsum[blockIdx.x - 1] : 0;
    int end = partial[i] + off;           // padded end of row i
    rowptr[i + 1] = end;
    if (i == 0) rowptr[0] = 0;
    int c = cnt[i];
    int start = end - ((c + 3) & ~3);
    for (int q = start + c; q < end; ++q) edges[q] = make_uint2(0u, 0u);  // fillers
  }
}

// atomic-free scatter: pos = rowptr[d] + rank
__global__ void scatter_kernel(const int* __restrict__ src, const int* __restrict__ dst,
                               const float* __restrict__ ea, const float* __restrict__ dinv,
                               const int* __restrict__ rowptr, const int* __restrict__ rank,
                               uint2* __restrict__ edges, int e) {
  int i = blockIdx.x * blockDim.x + threadIdx.x;
  if (i < e) {
    int s = src[i], d = dst[i];
    float w = -dinv[s] * ea[i] * dinv[d];
    edges[rowptr[d] + rank[i]] = make_uint2((unsigned)s, __float_as_uint(w));
  }
}

// ---------------- sparse propagation V5: 4 node-chains per wave ----------------
// Wave handles 4 consecutive nodes concurrently (quarter-wave each): q=lane>>4
// selects the node, grp=(lane>>3)&1 the edge-pair slot, sub=lane&7 the 16B row
// chunk. One gather instruction still covers 8 edges x 128B (1024B), but the
// wave now carries 4 independent latency chains (x2 unroll = 8 outstanding
// gathers) instead of 1 -- attacks the per-node rowptr->meta->gather serial
// head that made V4 latency-bound. Rows padded to %4 with {src=0,w=0}.
// out = alpha * prop(g) + c1*a1 + c2*a2   [+ bias, relu]

template<int NADD, bool RELUB>
__global__ __launch_bounds__(256) void prop_kernel(
    const int* __restrict__ rowptr, const uint2* __restrict__ edges,
    const ushort* __restrict__ g, int sg,
    const ushort* __restrict__ a1, int sa1, float c1,
    const ushort* __restrict__ a2, int sa2, float c2,
    const float* __restrict__ bias,
    ushort* __restrict__ out, int so, int n, float alpha)
{
  const int wave = threadIdx.x >> 6;
  const int lane = threadIdx.x & 63;
  const int q    = lane >> 4;        // node chain 0..3
  const int grp  = (lane >> 3) & 1;  // edge slot within pair
  const int sub  = lane & 7;         // 16B chunk of 128B row
  const int nd = (blockIdx.x * 4 + wave) * 4 + q;   // grid covers n exactly
  const int e0 = rowptr[nd];
  const int e1 = rowptr[nd + 1];

  float ra[8] = {}, rb[8] = {};
  int j = e0 + grp;                  // this lane's edge stream: stride 2
  for (; j + 2 < e1; j += 4) {       // unroll 2 (rows padded %4 -> no tail)
    uint2 p0 = edges[j];
    uint2 p1 = edges[j + 2];
    uint4 v0 = *(const uint4*)&g[(size_t)p0.x * sg + sub * 8];
    uint4 v1 = *(const uint4*)&g[(size_t)p1.x * sg + sub * 8];
    float w0 = __uint_as_float(p0.y);
    float w1 = __uint_as_float(p1.y);
    ra[0] += w0 * lo16(v0.x); ra[1] += w0 * hi16(v0.x);
    ra[2] += w0 * lo16(v0.y); ra[3] += w0 * hi16(v0.y);
    ra[4] += w0 * lo16(v0.z); ra[5] += w0 * hi16(v0.z);
    ra[6] += w0 * lo16(v0.w); ra[7] += w0 * hi16(v0.w);
    rb[0] += w1 * lo16(v1.x); rb[1] += w1 * hi16(v1.x);
    rb[2] += w1 * lo16(v1.y); rb[3] += w1 * hi16(v1.y);
    rb[4] += w1 * lo16(v1.z); rb[5] += w1 * hi16(v1.z);
    rb[6] += w1 * lo16(v1.w); rb[7] += w1 * hi16(v1.w);
  }
  float r[8];
  #pragma unroll
  for (int e = 0; e < 8; ++e) {
    float t = ra[e] + rb[e];
    t += __shfl_xor(t, 8, 64);       // combine the two edge slots (within quarter)
    r[e] = alpha * t;
  }
  if constexpr (NADD >= 1) {
    uint4 u = *(const uint4*)&a1[(size_t)nd * sa1 + sub * 8];
    r[0] += c1 * lo16(u.x); r[1] += c1 * hi16(u.x);
    r[2] += c1 * lo16(u.y); r[3] += c1 * hi16(u.y);
    r[4] += c1 * lo16(u.z); r[5] += c1 * hi16(u.z);
    r[6] += c1 * lo16(u.w); r[7] += c1 * hi16(u.w);
  }
  if constexpr (NADD >= 2) {
    uint4 u = *(const uint4*)&a2[(size_t)nd * sa2 + sub * 8];
    r[0] += c2 * lo16(u.x); r[1] += c2 * hi16(u.x);
    r[2] += c2 * lo16(u.y); r[3] += c2 * hi16(u.y);
    r[4] += c2 * lo16(u.z); r[5] += c2 * hi16(u.z);
    r[6] += c2 * lo16(u.w); r[7] += c2 * hi16(u.w);
  }
  if constexpr (RELUB) {
    float4 b0 = *(const float4*)&bias[sub * 8];
    float4 b1 = *(const float4*)&bias[sub * 8 + 4];
    r[0] = fmaxf(r[0] + b0.x, 0.f); r[1] = fmaxf(r[1] + b0.y, 0.f);
    r[2] = fmaxf(r[2] + b0.z, 0.f); r[3] = fmaxf(r[3] + b0.w, 0.f);
    r[4] = fmaxf(r[4] + b1.x, 0.f); r[5] = fmaxf(r[5] + b1.y, 0.f);
    r[6] = fmaxf(r[6] + b1.z, 0.f); r[7] = fmaxf(r[7] + b1.w, 0.f);
  }
  if (grp == 0) {                    // 8 lanes per quarter write the 128B row
    uint4 o;
    o.x = (uint)f2b(r[0]) | ((uint)f2b(r[1]) << 16);
    o.y = (uint)f2b(r[2]) | ((uint)f2b(r[3]) << 16);
    o.z = (uint)f2b(r[4]) | ((uint)f2b(r[5]) << 16);
    o.w = (uint)f2b(r[6]) | ((uint)f2b(r[7]) << 16);
    *(uint4*)&out[(size_t)nd * so + sub * 8] = o;
  }
}

// ---------------- MFMA GEMM (bf16 in, bf16 out) ----------------

template<int Ci, int Co, bool BR>
__global__ __launch_bounds__(256) void gemm_mfma(const ushort* __restrict__ A,
    const ushort* __restrict__ Wt, const float* __restrict__ bias,
    ushort* __restrict__ C, int n)
{
  const int lane = threadIdx.x & 63;
  const int wid  = threadIdx.x >> 6;
  const int rb = blockIdx.x * 256;
  const int cb = blockIdx.y * 64;
  const int lr = lane & 15;
  const int lk = (lane >> 4) << 3;
  f32x4 acc[4][4] = {};

  for (int kc = 0; kc < Ci; kc += 64) {
    bf16x8 bfrag[2][4];
    #pragma unroll
    for (int ks = 0; ks < 2; ++ks)
      #pragma unroll
      for (int nt = 0; nt < 4; ++nt)
        bfrag[ks][nt] = *(const bf16x8*)&Wt[(size_t)(cb + nt * 16 + lr) * Ci + kc + ks * 32 + lk];
    #pragma unroll
    for (int s = 0; s < 4; ++s) {
      const int row = rb + (wid * 4 + s) * 16 + lr;
      const ushort* ap = &A[(size_t)row * Ci + kc + lk];
      #pragma unroll
      for (int ks = 0; ks < 2; ++ks) {
        bf16x8 af = {};
        if (row < n) af = *(const bf16x8*)(ap + ks * 32);
        #pragma unroll
        for (int nt = 0; nt < 4; ++nt)
          acc[s][nt] = __builtin_amdgcn_mfma_f32_16x16x32_bf16(af, bfrag[ks][nt], acc[s][nt], 0, 0, 0);
      }
    }
  }

  #pragma unroll
  for (int s = 0; s < 4; ++s)
    #pragma unroll
    for (int nt = 0; nt < 4; ++nt) {
      const int col = cb + nt * 16 + lr;
      #pragma unroll
      for (int r = 0; r < 4; ++r) {
        const int row = rb + (wid * 4 + s) * 16 + ((lane >> 4) << 2) + r;
        if (row < n) {
          float v = acc[s][nt][r];
          if constexpr (BR) v = fmaxf(v + bias[col], 0.f);
          C[(size_t)row * Co + col] = f2b(v);
        }
      }
    }
}

// ---------------- pooling + head ----------------

__global__ __launch_bounds__(128) void pool_kernel(const ushort* __restrict__ h,
    const int* __restrict__ batch, float* __restrict__ pooled,
    float* __restrict__ gcnt, int n) {
  const int f = threadIdx.x;
  const int i0 = blockIdx.x * 64;
  const int iend = min(i0 + 64, n);
  int cur = batch[i0];
  float acc = 0.f;
  int run = 0;
  for (int i = i0; i < iend; ++i) {
    int b = batch[i];
    float v = b2f(h[(size_t)i * 128 + f]);
    if (b != cur) {
      atomicAdd(&pooled[cur * 128 + f], acc);
      if (f == 0) atomicAdd(&gcnt[cur], (float)run);
      acc = 0.f; run = 0; cur = b;
    }
    acc += v; run++;
  }
  atomicAdd(&pooled[cur * 128 + f], acc);
  if (f == 0) atomicAdd(&gcnt[cur], (float)run);
}

__global__ __launch_bounds__(128) void head_kernel(const float* __restrict__ pooled,
    const float* __restrict__ gcnt, const float* __restrict__ Wl,
    const float* __restrict__ bl, float* __restrict__ outp)
{
  int g = blockIdx.x, t = threadIdx.x;
  float denom = fmaxf(gcnt[g], 1.f);
  float p = pooled[g * 128 + t] / denom;
  __shared__ float s0[128], s1[128];
  s0[t] = p * Wl[t * 2 + 0];
  s1[t] = p * Wl[t * 2 + 1];
  __syncthreads();
  for (int off = 64; off > 0; off >>= 1) {
    if (t < off) { s0[t] += s0[t + off]; s1[t] += s1[t + off]; }
    __syncthreads();
  }
  if (t == 0) {
    float a = s0[0] + bl[0], b = s1[0] + bl[1];
    float m = fmaxf(a, b);
    float z = logf(expf(a - m) + expf(b - m)) + m;
    outp[g * 2 + 0] = a - z;
    outp[g * 2 + 1] = b - z;
  }
}

// ---------------- launch ----------------

extern "C" void kernel_launch(void* const* d_in, const int* in_sizes, int n_in,
                              void* d_out, int out_size, void* d_ws, size_t ws_size,
                              hipStream_t stream) {
  const float* x   = (const float*)d_in[0];
  const int*   ei  = (const int*)d_in[1];
  const float* ea  = (const float*)d_in[2];
  const int* batch = (const int*)d_in[3];
  const float* W1  = (const float*)d_in[4];
  const float* lb1 = (const float*)d_in[5];
  const float* W2  = (const float*)d_in[6];
  const float* lb2 = (const float*)d_in[7];
  const float* W3  = (const float*)d_in[8];
  const float* lb3 = (const float*)d_in[9];
  const float* Wl  = (const float*)d_in[10];
  const float* bl  = (const float*)d_in[11];
  const int* srcv = ei;
  const int* dstv = ei + EE;

  char* w = (char*)d_ws;
  auto alloc = [&](size_t bytes) -> char* {
    char* p = w; w += (bytes + 255) & ~(size_t)255; return p;
  };
  // zero-init region: deg, cnt, pooled+gcnt contiguous (one memset)
  float* deg    = (float*)alloc((size_t)NN * 4);          // becomes dinv in scan1
  int*   cnt    = (int*)alloc((size_t)NN * 4);
  float* pooled = (float*)alloc((size_t)(GG * 128 + GG) * 4);
  float* gcnt   = pooled + GG * 128;
  char*  zero_end = w;
  int*   rowptr = (int*)alloc((size_t)(NN + 1) * 4);
  int*   bsum   = (int*)alloc(256 * 4);
  int*   rank   = (int*)alloc((size_t)EE * 4);
  uint2* edges  = (uint2*)alloc((size_t)(EE + 4 * NN) * 8); // rows padded to %4
  ushort* Acat  = (ushort*)alloc((size_t)NN * 320 * 2);   // a_k / Clenshaw / Tx_k
  ushort* Bcat  = (ushort*)alloc((size_t)NN * 320 * 2);   // layer2 blocks; later h3
  ushort* h1    = (ushort*)alloc((size_t)NN * 64 * 2);
  ushort* Wt2   = (ushort*)alloc((size_t)320 * 64 * 2);
  ushort* Wt3   = (ushort*)alloc((size_t)128 * 320 * 2);
  int*   partial = (int*)Bcat;     // scan scratch (Bcat unused until gemm2)
  ushort* h3 = Bcat;               // layer-3 output reuses Bcat

  hipMemsetAsync(deg, 0, (size_t)(zero_end - (char*)deg), stream);

  // phase 1: histogram ∪ gemm1 ∪ cvt_w in one launch
  mega1<<<HB + GB1 + CVB, 256, 0, stream>>>(srcv, dstv, ea, deg, cnt, rank,
                                            x, W1, Acat, W2, W3, Wt2, Wt3);

  const int nb = (NN + 255) / 256;  // 196
  scan1<<<nb, 256, 0, stream>>>(cnt, deg, partial, bsum, NN);      // + dinv
  scan2<<<1, 256, 0, stream>>>(bsum, nb);
  scan3<<<nb, 256, 0, stream>>>(partial, bsum, cnt, rowptr, edges, NN);  // + pad
  scatter_kernel<<<(EE + 255) / 256, 256, 0, stream>>>(srcv, dstv, ea, deg, rowptr, rank,
                                                       edges, EE);

  const int PG = NN / 16;            // 3125 prop blocks (4 waves x 4 nodes each)
  const int GX = (NN + 255) / 256;   // gemm row-blocks

  ushort* A0 = Acat + 0 * 64;  ushort* A1 = Acat + 1 * 64;  ushort* A2 = Acat + 2 * 64;
  ushort* A3 = Acat + 3 * 64;  ushort* A4 = Acat + 4 * 64;
  ushort* B0 = Bcat + 0 * 64;  ushort* B1 = Bcat + 1 * 64;  ushort* B2 = Bcat + 2 * 64;
  ushort* B3 = Bcat + 3 * 64;  ushort* B4 = Bcat + 4 * 64;
  const int S = 320;

  // ---- Layer 1 (Clenshaw), a_k already in Acat from mega1 ----
  prop_kernel<1, false><<<PG, 256, 0, stream>>>(rowptr, edges, A4, S, A3, S, 1.f,
      nullptr, 0, 0.f, nullptr, A3, S, NN, 2.f);
  prop_kernel<2, false><<<PG, 256, 0, stream>>>(rowptr, edges, A3, S, A2, S, 1.f,
      A4, S, -1.f, nullptr, A2, S, NN, 2.f);
  prop_kernel<2, false><<<PG, 256, 0, stream>>>(rowptr, edges, A2, S, A1, S, 1.f,
      A3, S, -1.f, nullptr, A1, S, NN, 2.f);
  prop_kernel<2, true><<<PG, 256, 0, stream>>>(rowptr, edges, A1, S, A0, S, 1.f,
      A2, S, -1.f, lb1, h1, 64, NN, 1.f);

  // ---- Layer 2 (Clenshaw): a_k = h1 @ W2_k -> Bcat ----
  gemm_mfma<64, 320, false><<<dim3(GX, 5), 256, 0, stream>>>(h1, Wt2, nullptr, Bcat, NN);
  prop_kernel<1, false><<<PG, 256, 0, stream>>>(rowptr, edges, B4, S, B3, S, 1.f,
      nullptr, 0, 0.f, nullptr, B3, S, NN, 2.f);
  prop_kernel<2, false><<<PG, 256, 0, stream>>>(rowptr, edges, B3, S, B2, S, 1.f,
      B4, S, -1.f, nullptr, B2, S, NN, 2.f);
  prop_kernel<2, false><<<PG, 256, 0, stream>>>(rowptr, edges, B2, S, B1, S, 1.f,
      B3, S, -1.f, nullptr, B1, S, NN, 2.f);
  // h2 -> Acat block 0 (Tx0), strided
  prop_kernel<2, true><<<PG, 256, 0, stream>>>(rowptr, edges, B1, S, B0, S, 1.f,
      B2, S, -1.f, lb2, A0, S, NN, 1.f);

  // ---- Layer 3 (forward recursion, Tx_k in Acat blocks) ----
  prop_kernel<0, false><<<PG, 256, 0, stream>>>(rowptr, edges, A0, S, nullptr, 0, 0.f,
      nullptr, 0, 0.f, nullptr, A1, S, NN, 1.f);
  prop_kernel<1, false><<<PG, 256, 0, stream>>>(rowptr, edges, A1, S, A0, S, -1.f,
      nullptr, 0, 0.f, nullptr, A2, S, NN, 2.f);
  prop_kernel<1, false><<<PG, 256, 0, stream>>>(rowptr, edges, A2, S, A1, S, -1.f,
      nullptr, 0, 0.f, nullptr, A3, S, NN, 2.f);
  prop_kernel<1, false><<<PG, 256, 0, stream>>>(rowptr, edges, A3, S, A2, S, -1.f,
      nullptr, 0, 0.f, nullptr, A4, S, NN, 2.f);
  // h3 = relu([Tx0|..|Tx4] @ W3stack + b3)
  gemm_mfma<320, 128, true><<<dim3(GX, 2), 256, 0, stream>>>(Acat, Wt3, lb3, h3, NN);

  // ---- pool + head ----
  pool_kernel<<<(NN + 63) / 64, 128, 0, stream>>>(h3, batch, pooled, gcnt, NN);
  head_kernel<<<GG, 128, 0, stream>>>(pooled, gcnt, Wl, bl, (float*)d_out);
}